// Round 6
// baseline (934.531 us; speedup 1.0000x reference)
//
#include <hip/hip_runtime.h>

typedef unsigned short u16;
typedef unsigned int u32;
typedef short short8 __attribute__((ext_vector_type(8)));
typedef float float4v __attribute__((ext_vector_type(4)));

#define L_SEQ 1024
#define NB 4
#define NH 16
#define DK 128
#define DV 128
#define HID 2048
#define NQKVZ 8192
#define CONV_DIM 6144

static __device__ __forceinline__ float bf2f(u16 u) {
    union { u32 i; float f; } x; x.i = ((u32)u) << 16; return x.f;
}
static __device__ __forceinline__ u16 f2bf(float f) {
    union { float f; u32 u; } x; x.f = f;
    u32 r = x.u + 0x7FFF + ((x.u >> 16) & 1);
    return (u16)(r >> 16);
}

// async global->LDS, 16B per lane. LDS dest must be wave-uniform base +
// lane*16 — our staging layout is exactly lane-contiguous, so this holds.
#define GLOAD_LDS16(g, l)                                        \
    __builtin_amdgcn_global_load_lds(                            \
        (const __attribute__((address_space(1))) void*)(g),      \
        (__attribute__((address_space(3))) void*)(l), 16, 0, 0)

// DPP cross-lane adds (pure VALU, no DS).
#define DPP_ADD(x, ctrl) \
    ((x) + __int_as_float(__builtin_amdgcn_update_dpp( \
         0, __float_as_int(x), (ctrl), 0xF, 0xF, true)))
static __device__ __forceinline__ float sum16_dpp(float x) {
    x = DPP_ADD(x, 0xB1);   // lane^1
    x = DPP_ADD(x, 0x4E);   // lane^2
    x = DPP_ADD(x, 0x141);  // row_half_mirror
    x = DPP_ADD(x, 0x140);  // row_mirror
    return x;
}

// ---------------- fp32 -> bf16 elementwise convert ---------------------------
__global__ __launch_bounds__(256) void f32_to_bf16(
    const float* __restrict__ in, u16* __restrict__ out) {
    long i = ((long)blockIdx.x * 256 + threadIdx.x) * 8;
    float4 a = *(const float4*)(in + i);
    float4 b = *(const float4*)(in + i + 4);
    u16 tmp[8];
    tmp[0] = f2bf(a.x); tmp[1] = f2bf(a.y); tmp[2] = f2bf(a.z); tmp[3] = f2bf(a.w);
    tmp[4] = f2bf(b.x); tmp[5] = f2bf(b.y); tmp[6] = f2bf(b.z); tmp[7] = f2bf(b.w);
    *(uint4*)(out + i) = *(const uint4*)tmp;
}

// ---------------- transpose fp32 (RxC) -> bf16 (CxR) -------------------------
__global__ __launch_bounds__(256) void transpose_f32_bf16(
    const float* __restrict__ in, u16* __restrict__ out, int R, int C) {
    __shared__ float tile[32][33];
    int bx = blockIdx.x, by = blockIdx.y;
    int c = threadIdx.x & 31;
    int r0 = threadIdx.x >> 5;
#pragma unroll
    for (int i = 0; i < 4; i++) {
        int r = r0 + i * 8;
        tile[r][c] = in[(long)(by * 32 + r) * C + bx * 32 + c];
    }
    __syncthreads();
#pragma unroll
    for (int i = 0; i < 4; i++) {
        int r = r0 + i * 8;
        out[(long)(bx * 32 + r) * R + by * 32 + c] = f2bf(tile[c][r]);
    }
}

// ---------------- transpose fp32 (RxC) -> fp32 (CxR) -------------------------
__global__ __launch_bounds__(256) void transpose_f32_f32(
    const float* __restrict__ in, float* __restrict__ out, int R, int C) {
    __shared__ float tile[32][33];
    int bx = blockIdx.x, by = blockIdx.y;
    int c = threadIdx.x & 31;
    int r0 = threadIdx.x >> 5;
#pragma unroll
    for (int i = 0; i < 4; i++) {
        int r = r0 + i * 8;
        tile[r][c] = in[(long)(by * 32 + r) * C + bx * 32 + c];
    }
    __syncthreads();
#pragma unroll
    for (int i = 0; i < 4; i++) {
        int r = r0 + i * 8;
        out[(long)(bx * 32 + r) * R + by * 32 + c] = tile[c][r];
    }
}

// ---------------- GEMM (m97 structure): C = A * BT^T, bf16 in, OutT out ------
// 128x128 tile, BK=32, async global_load_lds width=16 into contiguous
// (unpadded) LDS tiles; 2-barrier K-loop; 4x4 MFMA accs per wave.
#define BM 128
#define BN 128
#define BKK 32

static __device__ __forceinline__ void store_out(u16* p, float v)  { *p = f2bf(v); }
static __device__ __forceinline__ void store_out(float* p, float v){ *p = v; }

template <typename OutT>
__global__ __launch_bounds__(256) void gemm_abT(
    const u16* __restrict__ A, const u16* __restrict__ BT,
    OutT* __restrict__ C, int M, int N, int K) {
    __shared__ u16 As[BM * BKK];   // 8 KB, row-major [128][32], no padding
    __shared__ u16 Bs[BN * BKK];
    int t = threadIdx.x;
    int lane = t & 63;
    int w = t >> 6;
    int wm = (w & 1) * 64;
    int wn = (w >> 1) * 64;
    int l15 = lane & 15;
    int quad = lane >> 4;
    long blockM = (long)blockIdx.y * BM;
    long blockN = (long)blockIdx.x * BN;

    float4v acc[4][4];
#pragma unroll
    for (int i = 0; i < 4; i++)
#pragma unroll
        for (int j = 0; j < 4; j++) acc[i][j] = (float4v){0.f, 0.f, 0.f, 0.f};

    const u16* Ab = A + blockM * K;
    const u16* Bb = BT + blockN * K;

    // staging: 16B chunk index c = pass*256 + t ; row = c>>2, col = (c&3)*8.
    // LDS offset = c*16 bytes — lane-contiguous, as global_load_lds requires.
    const int r0 = t >> 2,         c0 = (t & 3) * 8;
    const int r1 = (t + 256) >> 2, c1 = ((t + 256) & 3) * 8;
    u16* As0 = As + t * 8;         u16* As1 = As + (t + 256) * 8;
    u16* Bs0 = Bs + t * 8;         u16* Bs1 = Bs + (t + 256) * 8;
    const u16* Ag0 = Ab + (long)r0 * K + c0;
    const u16* Ag1 = Ab + (long)r1 * K + c1;
    const u16* Bg0 = Bb + (long)r0 * K + c0;
    const u16* Bg1 = Bb + (long)r1 * K + c1;

    for (int k0 = 0; k0 < K; k0 += BKK) {
        __syncthreads();             // prior iteration's LDS reads complete
        GLOAD_LDS16(Ag0 + k0, As0);
        GLOAD_LDS16(Ag1 + k0, As1);
        GLOAD_LDS16(Bg0 + k0, Bs0);
        GLOAD_LDS16(Bg1 + k0, Bs1);
        __syncthreads();             // drains vmcnt -> staged data visible

        union { short8 v; uint4 u; } fa[4], fb[4];
#pragma unroll
        for (int i = 0; i < 4; i++) {
            fa[i].u = *(const uint4*)(As + (wm + i * 16 + l15) * BKK + quad * 8);
            fb[i].u = *(const uint4*)(Bs + (wn + i * 16 + l15) * BKK + quad * 8);
        }
#pragma unroll
        for (int i = 0; i < 4; i++)
#pragma unroll
            for (int j = 0; j < 4; j++)
                acc[i][j] = __builtin_amdgcn_mfma_f32_16x16x32_bf16(
                    fa[i].v, fb[j].v, acc[i][j], 0, 0, 0);
    }

#pragma unroll
    for (int i = 0; i < 4; i++) {
        long mrow = blockM + wm + i * 16 + quad * 4;
#pragma unroll
        for (int j = 0; j < 4; j++) {
            long col = blockN + wn + j * 16 + l15;
#pragma unroll
            for (int r = 0; r < 4; r++) {
                store_out(&C[(mrow + r) * N + col], acc[i][j][r]);
            }
        }
    }
}

// ---------------- ba: eg = exp(g), beta = sigmoid(b) -------------------------
__global__ __launch_bounds__(64) void ba_kernel(
    const float* __restrict__ hs, const float* __restrict__ WbaT,
    const float* __restrict__ A_log, const float* __restrict__ dt_bias,
    float* __restrict__ egout, float* __restrict__ bout) {
    int bl = blockIdx.x;  // b*L + l
    int b = bl >> 10, l = bl & 1023;
    int t = threadIdx.x;
    __shared__ __align__(16) float hb[HID];
    const float* hrow = hs + (long)bl * HID;
#pragma unroll
    for (int i = 0; i < 8; i++) {
        int idx = (t + i * 64) * 4;
        *(float4*)(hb + idx) = *(const float4*)(hrow + idx);
    }
    __syncthreads();
    int n = t & 31, hf = t >> 5;
    const float* wrow = WbaT + (long)n * HID + hf * 1024;
    const float* hp = hb + hf * 1024;
    float acc = 0.f;
    for (int i = 0; i < 1024; i += 4) {
        float4 wv = *(const float4*)(wrow + i);
        float4 hv = *(const float4*)(hp + i);
        acc += wv.x * hv.x + wv.y * hv.y + wv.z * hv.z + wv.w * hv.w;
    }
    acc += __shfl_down(acc, 32);
    if (t < 32) {
        if (n < 16) {
            bout[((long)(b * NH + n)) * L_SEQ + l] = 1.f / (1.f + expf(-acc));
        } else {
            int h = n - 16;
            float x = acc + dt_bias[h];
            float sp = (x > 20.f) ? x : log1pf(expf(x));
            egout[((long)(b * NH + h)) * L_SEQ + l] = expf(-expf(A_log[h]) * sp);
        }
    }
}

// ---------------- conv(KS=4 causal depthwise) + l2norm(q,k) + split v --------
__global__ __launch_bounds__(256) void conv_qkv(
    const u16* __restrict__ qkvz, const float* __restrict__ conv_w,
    const float* __restrict__ conv_b,
    float* __restrict__ qs, float* __restrict__ ks, float* __restrict__ vs) {
    int bl = blockIdx.x;  // b*L + l
    int b = bl >> 10, l = bl & 1023;
    int t = threadIdx.x;
    __shared__ float xb[CONV_DIM];
    __shared__ float red[32][9];
    __shared__ float rbuf[32];

    for (int c = t; c < CONV_DIM; c += 256) {
        float acc = conv_b[c];
        float w0 = conv_w[c * 4 + 0];
        float w1 = conv_w[c * 4 + 1];
        float w2 = conv_w[c * 4 + 2];
        float w3 = conv_w[c * 4 + 3];
        long rowbase = (long)(b * L_SEQ) * NQKVZ + c;
        if (l - 3 >= 0) acc += bf2f(qkvz[rowbase + (long)(l - 3) * NQKVZ]) * w0;
        if (l - 2 >= 0) acc += bf2f(qkvz[rowbase + (long)(l - 2) * NQKVZ]) * w1;
        if (l - 1 >= 0) acc += bf2f(qkvz[rowbase + (long)(l - 1) * NQKVZ]) * w2;
        acc += bf2f(qkvz[rowbase + (long)l * NQKVZ]) * w3;
        xb[c] = acc;
    }
    __syncthreads();
    {
        int grp = t >> 3;   // 0..31 (q heads 0..15, k heads 16..31)
        int j8 = t & 7;
        float s = 0.f;
#pragma unroll
        for (int i = 0; i < 16; i++) {
            float xv = xb[grp * 128 + j8 * 16 + i];
            s += xv * xv;
        }
        red[grp][j8] = s;
    }
    __syncthreads();
    if (t < 32) {
        float s = 0.f;
#pragma unroll
        for (int i = 0; i < 8; i++) s += red[t][i];
        rbuf[t] = rsqrtf(s + 1e-6f);
    }
    __syncthreads();
    for (int c = t; c < CONV_DIM; c += 256) {
        float xv = xb[c];
        if (c < 2048) {
            int h = c >> 7, d = c & 127;
            qs[(((long)(b * NH + h)) * L_SEQ + l) * DK + d] = xv * rbuf[h];
        } else if (c < 4096) {
            int c2 = c - 2048;
            int h = c2 >> 7, d = c2 & 127;
            ks[(((long)(b * NH + h)) * L_SEQ + l) * DK + d] = xv * rbuf[16 + h];
        } else {
            int c2 = c - 4096;
            int h = c2 >> 7, d = c2 & 127;
            vs[(((long)(b * NH + h)) * L_SEQ + l) * DV + d] = xv;
        }
    }
}

// ---------------- sequential gated delta scan, v5 (unchanged) ----------------
#define SCAN_T 64

union F8u { float4 v4[2]; float f[8]; };

__global__ __launch_bounds__(256) void gdn_scan(
    const float* __restrict__ q, const float* __restrict__ k,
    const float* __restrict__ v, const float* __restrict__ eg,
    const float* __restrict__ beta, float* __restrict__ o) {
    int bid = blockIdx.x;
    int dc = bid & 7;
    int bh = bid >> 3;          // b*NH + h
    int b = bh >> 4, h = bh & 15;
    int t = threadIdx.x;
    int lane = t & 63;
    int wv = t >> 6;            // wave 0..3
    int kg = lane & 15;         // 8 k values per thread
    int dl = wv * 4 + (lane >> 4);  // 0..15
    int d = dc * 16 + dl;

    __shared__ float kt[SCAN_T * 128];
    __shared__ float qt[SCAN_T * 128];
    __shared__ float vt[SCAN_T * 16];
    __shared__ float et[SCAN_T];
    __shared__ float bts[SCAN_T];

    const long base = (long)bh * L_SEQ;
    const float* kgl = k + base * DK;
    const float* qgl = q + base * DK;
    const float* vgl = v + base * DV + dc * 16;
    const float* ep  = eg + base;
    const float* bp  = beta + base;
    const float scale = 0.08838834764831845f;  // 128^-0.5

    float S[8];
#pragma unroll
    for (int j = 0; j < 8; j++) S[j] = 0.f;

    const int slot0 = kg * 2;
    const int slot1 = kg * 2 + 1;
    const int phys0 = (slot0 ^ (slot0 >> 3)) * 4;
    const int phys1 = (slot1 ^ (slot1 >> 3)) * 4;

    F8u KA, QA, KB, QB;

    auto load_frag = [&](F8u& KF, F8u& QF, int lt) {
        int rb = lt * 128;
        KF.v4[0] = *(const float4*)&kt[rb + phys0];
        KF.v4[1] = *(const float4*)&kt[rb + phys1];
        QF.v4[0] = *(const float4*)&qt[rb + phys0];
        QF.v4[1] = *(const float4*)&qt[rb + phys1];
    };

    auto step = [&](const F8u& KF, const F8u& QF, int lt, int abs_ts) {
        float e = et[lt];
        float btv = bts[lt];
        float vval = vt[lt * 16 + dl];
        float pr[8];
#pragma unroll
        for (int j = 0; j < 8; j++) {
            S[j] *= e;
            pr[j] = KF.f[j] * S[j];
        }
        float p = ((pr[0] + pr[1]) + (pr[2] + pr[3])) +
                  ((pr[4] + pr[5]) + (pr[6] + pr[7]));
        p = sum16_dpp(p);
        float delta = (vval - p) * btv;
        float orr[8];
#pragma unroll
        for (int j = 0; j < 8; j++) {
            S[j] = fmaf(KF.f[j], delta, S[j]);
            orr[j] = QF.f[j] * S[j];
        }
        float oo = ((orr[0] + orr[1]) + (orr[2] + orr[3])) +
                   ((orr[4] + orr[5]) + (orr[6] + orr[7]));
        oo = sum16_dpp(oo);
        if (kg == 0) {
            o[(((long)(b * L_SEQ + abs_ts)) * NH + h) * DV + d] = oo * scale;
        }
    };

    for (int ts0 = 0; ts0 < L_SEQ; ts0 += SCAN_T) {
        __syncthreads();
        {
            const float* ksrc = kgl + (long)ts0 * DK;
            const float* qsrc = qgl + (long)ts0 * DK;
#pragma unroll
            for (int pss = 0; pss < 8; pss++) {
                int w4 = t + pss * 256;
                int row = w4 >> 5;
                int slot = w4 & 31;
                int dst = row * 128 + (slot ^ (slot >> 3)) * 4;
                float4 kv = *(const float4*)(ksrc + (long)w4 * 4);
                float4 qv = *(const float4*)(qsrc + (long)w4 * 4);
                *(float4*)&kt[dst] = kv;
                *(float4*)&qt[dst] = qv;
            }
            {
                int row = t >> 2, c4 = t & 3;
                float4 vv = *(const float4*)(vgl + (long)(ts0 + row) * DV + c4 * 4);
                *(float4*)&vt[row * 16 + c4 * 4] = vv;
            }
            if (t < SCAN_T) et[t] = ep[ts0 + t];
            else if (t < 2 * SCAN_T) bts[t - SCAN_T] = bp[ts0 + t - SCAN_T];
        }
        __syncthreads();

        load_frag(KA, QA, 0);
        for (int lt = 0; lt < SCAN_T; lt += 2) {
            load_frag(KB, QB, lt + 1);
            step(KA, QA, lt, ts0 + lt);
            if (lt + 2 < SCAN_T) load_frag(KA, QA, lt + 2);
            step(KB, QB, lt + 1, ts0 + lt + 1);
        }
    }
}

// ---------------- gated RMS norm -> bf16 A2 ----------------------------------
__global__ __launch_bounds__(128) void gated_norm(
    const float* __restrict__ o, const u16* __restrict__ qkvz,
    const float* __restrict__ norm_w, u16* __restrict__ A2) {
    int bid = blockIdx.x;  // (b*L+l)*16 + h
    int t = threadIdx.x;   // 0..127
    float ov = o[(long)bid * 128 + t];
    float s = ov * ov;
#pragma unroll
    for (int off = 32; off > 0; off >>= 1) s += __shfl_down(s, off);
    __shared__ float ws2[2];
    if ((t & 63) == 0) ws2[t >> 6] = s;
    __syncthreads();
    float tot = ws2[0] + ws2[1];
    float rinv = rsqrtf(tot * (1.f / 128.f) + 1e-6f);
    int bl = bid >> 4, h = bid & 15;
    float z = bf2f(qkvz[(long)bl * NQKVZ + CONV_DIM + h * 128 + t]);
    float sig = 1.f / (1.f + expf(-z));
    float val = ov * rinv * norm_w[t] * sig;
    A2[(long)bl * 2048 + h * 128 + t] = f2bf(val);
}

// ---------------- host-side launcher -----------------------------------------
extern "C" void kernel_launch(void* const* d_in, const int* in_sizes, int n_in,
                              void* d_out, int out_size, void* d_ws, size_t ws_size,
                              hipStream_t stream) {
    const float* hs    = (const float*)d_in[0];  // (4,1024,2048)
    const float* Wqkvz = (const float*)d_in[1];  // (2048,8192)
    const float* Wba   = (const float*)d_in[2];  // (2048,32)
    const float* convw = (const float*)d_in[3];  // (6144,4)
    const float* convb = (const float*)d_in[4];  // (6144,)
    const float* A_log = (const float*)d_in[5];  // (16,)
    const float* dtb   = (const float*)d_in[6];  // (16,)
    const float* normw = (const float*)d_in[7];  // (128,)
    const float* Wout  = (const float*)d_in[8];  // (2048,2048)

    char* ws = (char*)d_ws;
    size_t off = 0;
    auto alloc = [&](size_t bytes) {
        size_t o = off;
        off = (off + bytes + 255) & ~(size_t)255;
        return o;
    };
    // region0: WqkvzT (bf16, 32MB) — dead after GEMM1, reused for os (fp32, 32MB)
    size_t r0 = alloc((size_t)NQKVZ * HID * 2);
    // region1: hs_bf16 (16MB) — dead after GEMM1, reused for A2 (bf16, 16MB)
    size_t r1 = alloc((size_t)4096 * HID * 2);
    u16*   WqkvzT = (u16*)(ws + r0);
    float* os     = (float*)(ws + r0);
    u16*   hsb    = (u16*)(ws + r1);
    u16*   A2     = (u16*)(ws + r1);
    u16*   qkvz   = (u16*)(ws + alloc((size_t)4096 * NQKVZ * 2));
    float* qs     = (float*)(ws + alloc((size_t)4096 * 2048 * 4));
    float* ks     = (float*)(ws + alloc((size_t)4096 * 2048 * 4));
    float* vs     = (float*)(ws + alloc((size_t)4096 * 2048 * 4));
    float* egs    = (float*)(ws + alloc((size_t)NB * NH * L_SEQ * 4));
    float* bs     = (float*)(ws + alloc((size_t)NB * NH * L_SEQ * 4));
    u16*   WoutT  = (u16*)(ws + alloc((size_t)HID * 2048 * 2));
    float* WbaT   = (float*)(ws + alloc((size_t)32 * HID * 4));

    // 1. convert + transposes (fp32 -> bf16 weights/activations)
    hipLaunchKernelGGL(f32_to_bf16, dim3(4096), dim3(256), 0, stream, hs, hsb);
    hipLaunchKernelGGL(transpose_f32_bf16, dim3(NQKVZ / 32, HID / 32), dim3(256), 0, stream,
                       Wqkvz, WqkvzT, HID, NQKVZ);
    hipLaunchKernelGGL(transpose_f32_bf16, dim3(2048 / 32, 2048 / 32), dim3(256), 0, stream,
                       Wout, WoutT, 2048, 2048);
    hipLaunchKernelGGL(transpose_f32_f32, dim3(1, HID / 32), dim3(256), 0, stream,
                       Wba, WbaT, HID, 32);

    // 2. big GEMM: qkvz = hs @ W_qkvz (bf16 in, bf16 out, m97 structure)
    hipLaunchKernelGGL((gemm_abT<u16>), dim3(NQKVZ / BN, 4096 / BM), dim3(256), 0, stream,
                       hsb, WqkvzT, qkvz, 4096, NQKVZ, HID);

    // 3. ba -> exp(g), beta (pure fp32)
    hipLaunchKernelGGL(ba_kernel, dim3(4096), dim3(64), 0, stream,
                       hs, WbaT, A_log, dtb, egs, bs);

    // 4. conv + l2norm -> q,k,v (fp32)
    hipLaunchKernelGGL(conv_qkv, dim3(4096), dim3(256), 0, stream,
                       qkvz, convw, convb, qs, ks, vs);

    // 5. scan (fp32, LDS-tiled, DPP-reduced, 512 blocks)
    hipLaunchKernelGGL(gdn_scan, dim3(NB * NH * 8), dim3(256), 0, stream,
                       qs, ks, vs, egs, bs, os);

    // 6. gated RMS norm -> bf16 A2
    hipLaunchKernelGGL(gated_norm, dim3(4096 * NH), dim3(128), 0, stream,
                       os, qkvz, normw, A2);

    // 7. out = A2 @ W_out (bf16 in, fp32 out, m97 structure)
    hipLaunchKernelGGL((gemm_abT<float>), dim3(2048 / BN, 4096 / BM), dim3(256), 0, stream,
                       A2, WoutT, (float*)d_out, 4096, 2048, HID);
}

// Round 7
// 803.205 us; speedup vs baseline: 1.1635x; 1.1635x over previous
//
#include <hip/hip_runtime.h>

typedef unsigned short u16;
typedef unsigned int u32;
typedef short short8 __attribute__((ext_vector_type(8)));
typedef float float4v __attribute__((ext_vector_type(4)));

#define L_SEQ 1024
#define NB 4
#define NH 16
#define DK 128
#define DV 128
#define HID 2048
#define NQKVZ 8192
#define CONV_DIM 6144
#define GDN_SCALE 0.08838834764831845f  // 128^-0.5

static __device__ __forceinline__ float bf2f(u16 u) {
    union { u32 i; float f; } x; x.i = ((u32)u) << 16; return x.f;
}
static __device__ __forceinline__ u16 f2bf(float f) {
    union { float f; u32 u; } x; x.f = f;
    u32 r = x.u + 0x7FFF + ((x.u >> 16) & 1);
    return (u16)(r >> 16);
}

union FragU { short8 v; uint4 u; };

// async global->LDS, 16B per lane (lane-contiguous LDS dest required).
#define GLOAD_LDS16(g, l)                                        \
    __builtin_amdgcn_global_load_lds(                            \
        (const __attribute__((address_space(1))) void*)(g),      \
        (__attribute__((address_space(3))) void*)(l), 16, 0, 0)

// ---------------- fp32 -> bf16 elementwise convert ---------------------------
__global__ __launch_bounds__(256) void f32_to_bf16(
    const float* __restrict__ in, u16* __restrict__ out) {
    long i = ((long)blockIdx.x * 256 + threadIdx.x) * 8;
    float4 a = *(const float4*)(in + i);
    float4 b = *(const float4*)(in + i + 4);
    u16 tmp[8];
    tmp[0] = f2bf(a.x); tmp[1] = f2bf(a.y); tmp[2] = f2bf(a.z); tmp[3] = f2bf(a.w);
    tmp[4] = f2bf(b.x); tmp[5] = f2bf(b.y); tmp[6] = f2bf(b.z); tmp[7] = f2bf(b.w);
    *(uint4*)(out + i) = *(const uint4*)tmp;
}

// ---------------- transpose fp32 (RxC) -> bf16 (CxR) -------------------------
__global__ __launch_bounds__(256) void transpose_f32_bf16(
    const float* __restrict__ in, u16* __restrict__ out, int R, int C) {
    __shared__ float tile[32][33];
    int bx = blockIdx.x, by = blockIdx.y;
    int c = threadIdx.x & 31;
    int r0 = threadIdx.x >> 5;
#pragma unroll
    for (int i = 0; i < 4; i++) {
        int r = r0 + i * 8;
        tile[r][c] = in[(long)(by * 32 + r) * C + bx * 32 + c];
    }
    __syncthreads();
#pragma unroll
    for (int i = 0; i < 4; i++) {
        int r = r0 + i * 8;
        out[(long)(bx * 32 + r) * R + by * 32 + c] = f2bf(tile[c][r]);
    }
}

// ---------------- transpose fp32 (RxC) -> fp32 (CxR) -------------------------
__global__ __launch_bounds__(256) void transpose_f32_f32(
    const float* __restrict__ in, float* __restrict__ out, int R, int C) {
    __shared__ float tile[32][33];
    int bx = blockIdx.x, by = blockIdx.y;
    int c = threadIdx.x & 31;
    int r0 = threadIdx.x >> 5;
#pragma unroll
    for (int i = 0; i < 4; i++) {
        int r = r0 + i * 8;
        tile[r][c] = in[(long)(by * 32 + r) * C + bx * 32 + c];
    }
    __syncthreads();
#pragma unroll
    for (int i = 0; i < 4; i++) {
        int r = r0 + i * 8;
        out[(long)(bx * 32 + r) * R + by * 32 + c] = tile[c][r];
    }
}

// ---------------- GEMM (m97 structure): C = A * BT^T, bf16 in, OutT out ------
#define BM 128
#define BN 128
#define BKK 32

static __device__ __forceinline__ void store_out(u16* p, float v)  { *p = f2bf(v); }
static __device__ __forceinline__ void store_out(float* p, float v){ *p = v; }

template <typename OutT>
__global__ __launch_bounds__(256) void gemm_abT(
    const u16* __restrict__ A, const u16* __restrict__ BT,
    OutT* __restrict__ C, int M, int N, int K) {
    __shared__ u16 As[BM * BKK];
    __shared__ u16 Bs[BN * BKK];
    int t = threadIdx.x;
    int lane = t & 63;
    int w = t >> 6;
    int wm = (w & 1) * 64;
    int wn = (w >> 1) * 64;
    int l15 = lane & 15;
    int quad = lane >> 4;
    long blockM = (long)blockIdx.y * BM;
    long blockN = (long)blockIdx.x * BN;

    float4v acc[4][4];
#pragma unroll
    for (int i = 0; i < 4; i++)
#pragma unroll
        for (int j = 0; j < 4; j++) acc[i][j] = (float4v){0.f, 0.f, 0.f, 0.f};

    const u16* Ab = A + blockM * K;
    const u16* Bb = BT + blockN * K;

    const int r0 = t >> 2,         c0 = (t & 3) * 8;
    const int r1 = (t + 256) >> 2, c1 = ((t + 256) & 3) * 8;
    u16* As0 = As + t * 8;         u16* As1 = As + (t + 256) * 8;
    u16* Bs0 = Bs + t * 8;         u16* Bs1 = Bs + (t + 256) * 8;
    const u16* Ag0 = Ab + (long)r0 * K + c0;
    const u16* Ag1 = Ab + (long)r1 * K + c1;
    const u16* Bg0 = Bb + (long)r0 * K + c0;
    const u16* Bg1 = Bb + (long)r1 * K + c1;

    for (int k0 = 0; k0 < K; k0 += BKK) {
        __syncthreads();
        GLOAD_LDS16(Ag0 + k0, As0);
        GLOAD_LDS16(Ag1 + k0, As1);
        GLOAD_LDS16(Bg0 + k0, Bs0);
        GLOAD_LDS16(Bg1 + k0, Bs1);
        __syncthreads();

        FragU fa[4], fb[4];
#pragma unroll
        for (int i = 0; i < 4; i++) {
            fa[i].u = *(const uint4*)(As + (wm + i * 16 + l15) * BKK + quad * 8);
            fb[i].u = *(const uint4*)(Bs + (wn + i * 16 + l15) * BKK + quad * 8);
        }
#pragma unroll
        for (int i = 0; i < 4; i++)
#pragma unroll
            for (int j = 0; j < 4; j++)
                acc[i][j] = __builtin_amdgcn_mfma_f32_16x16x32_bf16(
                    fa[i].v, fb[j].v, acc[i][j], 0, 0, 0);
    }

#pragma unroll
    for (int i = 0; i < 4; i++) {
        long mrow = blockM + wm + i * 16 + quad * 4;
#pragma unroll
        for (int j = 0; j < 4; j++) {
            long col = blockN + wn + j * 16 + l15;
#pragma unroll
            for (int r = 0; r < 4; r++) {
                store_out(&C[(mrow + r) * N + col], acc[i][j][r]);
            }
        }
    }
}

// ---------------- ba: g raw, beta = sigmoid(b) -------------------------------
__global__ __launch_bounds__(64) void ba_kernel(
    const float* __restrict__ hs, const float* __restrict__ WbaT,
    const float* __restrict__ A_log, const float* __restrict__ dt_bias,
    float* __restrict__ gout, float* __restrict__ bout) {
    int bl = blockIdx.x;  // b*L + l
    int b = bl >> 10, l = bl & 1023;
    int t = threadIdx.x;
    __shared__ __align__(16) float hb[HID];
    const float* hrow = hs + (long)bl * HID;
#pragma unroll
    for (int i = 0; i < 8; i++) {
        int idx = (t + i * 64) * 4;
        *(float4*)(hb + idx) = *(const float4*)(hrow + idx);
    }
    __syncthreads();
    int n = t & 31, hf = t >> 5;
    const float* wrow = WbaT + (long)n * HID + hf * 1024;
    const float* hp = hb + hf * 1024;
    float acc = 0.f;
    for (int i = 0; i < 1024; i += 4) {
        float4 wv = *(const float4*)(wrow + i);
        float4 hv = *(const float4*)(hp + i);
        acc += wv.x * hv.x + wv.y * hv.y + wv.z * hv.z + wv.w * hv.w;
    }
    acc += __shfl_down(acc, 32);
    if (t < 32) {
        if (n < 16) {
            bout[((long)(b * NH + n)) * L_SEQ + l] = 1.f / (1.f + expf(-acc));
        } else {
            int h = n - 16;
            float x = acc + dt_bias[h];
            float sp = (x > 20.f) ? x : log1pf(expf(x));
            gout[((long)(b * NH + h)) * L_SEQ + l] = -expf(A_log[h]) * sp;
        }
    }
}

// ---------------- conv(KS=4) + l2norm(q,k) + split v -> bf16 -----------------
__global__ __launch_bounds__(256) void conv_qkv(
    const u16* __restrict__ qkvz, const float* __restrict__ conv_w,
    const float* __restrict__ conv_b,
    u16* __restrict__ qs, u16* __restrict__ ks, u16* __restrict__ vs) {
    int bl = blockIdx.x;  // b*L + l
    int b = bl >> 10, l = bl & 1023;
    int t = threadIdx.x;
    __shared__ float xb[CONV_DIM];
    __shared__ float red[32][9];
    __shared__ float rbuf[32];

    for (int c = t; c < CONV_DIM; c += 256) {
        float acc = conv_b[c];
        float w0 = conv_w[c * 4 + 0];
        float w1 = conv_w[c * 4 + 1];
        float w2 = conv_w[c * 4 + 2];
        float w3 = conv_w[c * 4 + 3];
        long rowbase = (long)(b * L_SEQ) * NQKVZ + c;
        if (l - 3 >= 0) acc += bf2f(qkvz[rowbase + (long)(l - 3) * NQKVZ]) * w0;
        if (l - 2 >= 0) acc += bf2f(qkvz[rowbase + (long)(l - 2) * NQKVZ]) * w1;
        if (l - 1 >= 0) acc += bf2f(qkvz[rowbase + (long)(l - 1) * NQKVZ]) * w2;
        acc += bf2f(qkvz[rowbase + (long)l * NQKVZ]) * w3;
        xb[c] = acc;
    }
    __syncthreads();
    {
        int grp = t >> 3;
        int j8 = t & 7;
        float s = 0.f;
#pragma unroll
        for (int i = 0; i < 16; i++) {
            float xv = xb[grp * 128 + j8 * 16 + i];
            s += xv * xv;
        }
        red[grp][j8] = s;
    }
    __syncthreads();
    if (t < 32) {
        float s = 0.f;
#pragma unroll
        for (int i = 0; i < 8; i++) s += red[t][i];
        rbuf[t] = rsqrtf(s + 1e-6f);
    }
    __syncthreads();
    for (int c = t; c < CONV_DIM; c += 256) {
        float xv = xb[c];
        if (c < 2048) {
            int h = c >> 7, d = c & 127;
            qs[(((long)(b * NH + h)) * L_SEQ + l) * DK + d] = f2bf(xv * rbuf[h]);
        } else if (c < 4096) {
            int c2 = c - 2048;
            int h = c2 >> 7, d = c2 & 127;
            ks[(((long)(b * NH + h)) * L_SEQ + l) * DK + d] = f2bf(xv * rbuf[16 + h]);
        } else {
            int c2 = c - 4096;
            int h = c2 >> 7, d = c2 & 127;
            vs[(((long)(b * NH + h)) * L_SEQ + l) * DV + d] = f2bf(xv);
        }
    }
}

// ---------------- gdn_prep: per-chunk T, P, decay scalars (parallel) ---------
// 1024 blocks = (bh=64) x (chunk=16); 256 threads (4 waves).
// A[t][j] = beta_t e^{G_t-G_j}(k_t.k_j) (j<t); T = (I+A)^{-1} (fwd subst);
// P[t][j] = scale e^{G_t-G_j}(q_t.k_j) (j<=t). lam=e^{G_t}, dl=e^{G63-G_t}.
__global__ __launch_bounds__(256) void gdn_prep(
    const u16* __restrict__ ks_g, const u16* __restrict__ qs_g,
    const float* __restrict__ g_g, const float* __restrict__ b_g,
    u16* __restrict__ Tbuf, u16* __restrict__ Pbuf,
    float* __restrict__ lam_g, float* __restrict__ dl_g,
    float* __restrict__ gam_g) {
    int cid = blockIdx.x;
    int bh = cid >> 4;
    int ch = cid & 15;
    long rowbase = (long)bh * L_SEQ + ch * 64;
    int t = threadIdx.x;
    int lane = t & 63, w = t >> 6, l15 = lane & 15, quad = lane >> 4;

    __shared__ u16 Kl[64 * 136];
    __shared__ u16 Ql[64 * 136];
    __shared__ float Am[64 * 66];
    __shared__ float Tm[64 * 66];
    __shared__ float Gs[64], lamL[64], betaL[64];

    {   // stage K,Q rows bf16 -> padded LDS; stage g, beta
        int row = t >> 2, seg = (t & 3) * 32;
        const u16* ksrc = ks_g + (rowbase + row) * DK + seg;
        const u16* qsrc = qs_g + (rowbase + row) * DK + seg;
        *(uint4*)&Kl[row * 136 + seg]      = *(const uint4*)ksrc;
        *(uint4*)&Kl[row * 136 + seg + 8]  = *(const uint4*)(ksrc + 8);
        *(uint4*)&Kl[row * 136 + seg + 16] = *(const uint4*)(ksrc + 16);
        *(uint4*)&Kl[row * 136 + seg + 24] = *(const uint4*)(ksrc + 24);
        *(uint4*)&Ql[row * 136 + seg]      = *(const uint4*)qsrc;
        *(uint4*)&Ql[row * 136 + seg + 8]  = *(const uint4*)(qsrc + 8);
        *(uint4*)&Ql[row * 136 + seg + 16] = *(const uint4*)(qsrc + 16);
        *(uint4*)&Ql[row * 136 + seg + 24] = *(const uint4*)(qsrc + 24);
        if (t < 64) Gs[t] = g_g[rowbase + t];
        else if (t < 128) betaL[t - 64] = b_g[rowbase + t - 64];
    }
    __syncthreads();
    if (t == 0) {   // inclusive prefix sum of g
        float run = 0.f;
        for (int i = 0; i < 64; i++) { run += Gs[i]; Gs[i] = run; }
    }
    __syncthreads();
    if (t < 64) {
        float G63 = Gs[63];
        float lm = expf(Gs[t]);
        lamL[t] = lm;
        lam_g[(long)cid * 64 + t] = lm;
        dl_g[(long)cid * 64 + t] = expf(G63 - Gs[t]);
        if (t == 0) gam_g[cid] = expf(G63);
    }
    // MFMA: KK^T and QK^T (wave w = row-stripe w*16)
    float4v accKK[4], accQK[4];
#pragma unroll
    for (int tj = 0; tj < 4; tj++) {
        accKK[tj] = (float4v){0.f, 0.f, 0.f, 0.f};
        accQK[tj] = (float4v){0.f, 0.f, 0.f, 0.f};
    }
#pragma unroll
    for (int k0 = 0; k0 < 128; k0 += 32) {
        FragU ka, qa;
        ka.u = *(const uint4*)&Kl[(w * 16 + l15) * 136 + k0 + quad * 8];
        qa.u = *(const uint4*)&Ql[(w * 16 + l15) * 136 + k0 + quad * 8];
#pragma unroll
        for (int tj = 0; tj < 4; tj++) {
            FragU kb;
            kb.u = *(const uint4*)&Kl[(tj * 16 + l15) * 136 + k0 + quad * 8];
            accKK[tj] = __builtin_amdgcn_mfma_f32_16x16x32_bf16(ka.v, kb.v, accKK[tj], 0, 0, 0);
            accQK[tj] = __builtin_amdgcn_mfma_f32_16x16x32_bf16(qa.v, kb.v, accQK[tj], 0, 0, 0);
        }
    }
    __syncthreads();   // lamL/betaL visible to all
    // mask + scale; Am -> LDS fp32, P -> global bf16
#pragma unroll
    for (int tj = 0; tj < 4; tj++) {
#pragma unroll
        for (int r = 0; r < 4; r++) {
            int ti_ = w * 16 + quad * 4 + r;
            int j = tj * 16 + l15;
            float e = (j <= ti_) ? expf(Gs[ti_] - Gs[j]) : 0.f;
            Am[ti_ * 66 + j] = (j < ti_) ? betaL[ti_] * e * accKK[tj][r] : 0.f;
            Pbuf[(long)cid * 4096 + ti_ * 64 + j] =
                (j <= ti_) ? f2bf(GDN_SCALE * e * accQK[tj][r]) : (u16)0;
        }
    }
    __syncthreads();
    // forward substitution: column t independent per lane (wave 0 only)
    if (t < 64) {
        Tm[t] = (t == 0) ? 1.f : 0.f;
        for (int i = 1; i < 64; i++) {
            float s = (i == t) ? 1.f : 0.f;
            for (int j = 0; j < i; j++)
                s -= Am[i * 66 + j] * Tm[j * 66 + t];
            Tm[i * 66 + t] = s;
        }
    }
    __syncthreads();
    {   // T -> global bf16
        int row = t >> 2, c0 = (t & 3) * 16;
        u16 tmp[16];
#pragma unroll
        for (int i = 0; i < 16; i++) tmp[i] = f2bf(Tm[row * 66 + c0 + i]);
        *(uint4*)&Tbuf[(long)cid * 4096 + row * 64 + c0]     = *(uint4*)tmp;
        *(uint4*)&Tbuf[(long)cid * 4096 + row * 64 + c0 + 8] = *(uint4*)(tmp + 8);
    }
}

// ---------------- gdn_chunk: sequential chunk recurrence (MFMA) --------------
// 256 blocks = (bh=64) x (dc=4: 32 v-cols). 256 threads (4 waves). Per chunk:
// RHS = vb + wbneg*(S0hi+S0lo); D = T*RHS; O = ql*(S0hi+S0lo) + P*D;
// S0 = gam*S0 + kdT*D. S0 fp32 (hi/lo bf16 split for MFMA inputs).
__global__ __launch_bounds__(256) void gdn_chunk(
    const u16* __restrict__ qs_g, const u16* __restrict__ ks_g,
    const u16* __restrict__ vs_g, const float* __restrict__ b_g,
    const u16* __restrict__ Tbuf, const u16* __restrict__ Pbuf,
    const float* __restrict__ lam_g, const float* __restrict__ dl_g,
    const float* __restrict__ gam_g, float* __restrict__ o_g) {
    int bid = blockIdx.x;
    int dc = bid & 3;
    int bh = bid >> 2;
    int b = bh >> 4, h = bh & 15;
    int t = threadIdx.x;
    int lane = t & 63, w = t >> 6, l15 = lane & 15, quad = lane >> 4;

    __shared__ float S0L[128 * 33];
    __shared__ u16 s0hiT[32 * 136], s0loT[32 * 136];
    __shared__ u16 TL[64 * 72], PL[64 * 72];
    __shared__ u16 wbL[64 * 136], qlL[64 * 136];
    __shared__ u16 kdT[128 * 72];
    __shared__ float vbL[64 * 36];
    __shared__ u16 rhsT[32 * 72], DT[32 * 72];
    __shared__ float Obuf[64 * 36];
    __shared__ float lamL[64], betaL[64], dlL[64];
    __shared__ float gamL;

    long bl = (long)b * L_SEQ;

    for (int i = t; i < 128 * 33; i += 256) S0L[i] = 0.f;
    __syncthreads();

    for (int ch = 0; ch < 16; ch++) {
        int cid = bh * 16 + ch;
        int ts0 = ch * 64;
        long rowbase = (long)bh * L_SEQ + ts0;

        // ---- a1: scalars + stage T,P ----
        if (t < 64) lamL[t] = lam_g[(long)cid * 64 + t];
        else if (t < 128) dlL[t - 64] = dl_g[(long)cid * 64 + t - 64];
        else if (t < 192) betaL[t - 128] = b_g[rowbase + t - 128];
        else if (t == 192) gamL = gam_g[cid];
        {
            int row = t >> 2, c0 = (t & 3) * 16;
            const u16* tsrc = Tbuf + (long)cid * 4096 + row * 64 + c0;
            *(uint4*)&TL[row * 72 + c0]     = *(const uint4*)tsrc;
            *(uint4*)&TL[row * 72 + c0 + 8] = *(const uint4*)(tsrc + 8);
            const u16* psrc = Pbuf + (long)cid * 4096 + row * 64 + c0;
            *(uint4*)&PL[row * 72 + c0]     = *(const uint4*)psrc;
            *(uint4*)&PL[row * 72 + c0 + 8] = *(const uint4*)(psrc + 8);
        }
        __syncthreads();

        // ---- a2: build wbneg, ql, kdT, vb, S0 hi/lo split ----
#pragma unroll
        for (int pass = 0; pass < 4; pass++) {
            int idx = t + pass * 256;            // 0..1023
            int row = idx >> 4, seg = (idx & 15) * 8;
            float b_ = betaL[row], lm = lamL[row], dlv = dlL[row];
            uint4 kv = *(const uint4*)(ks_g + (rowbase + row) * DK + seg);
            const u16* kp = (const u16*)&kv;
            float sw = -b_ * lm;
            u16 wt[8];
#pragma unroll
            for (int j2 = 0; j2 < 8; j2++) {
                float kf = bf2f(kp[j2]);
                wt[j2] = f2bf(sw * kf);
                kdT[(seg + j2) * 72 + row] = f2bf(dlv * kf);
            }
            *(uint4*)&wbL[row * 136 + seg] = *(uint4*)wt;
            uint4 qv = *(const uint4*)(qs_g + (rowbase + row) * DK + seg);
            const u16* qp = (const u16*)&qv;
            float sq = GDN_SCALE * lm;
            u16 qt2[8];
#pragma unroll
            for (int j2 = 0; j2 < 8; j2++) qt2[j2] = f2bf(sq * bf2f(qp[j2]));
            *(uint4*)&qlL[row * 136 + seg] = *(uint4*)qt2;
        }
        {
            int row = t >> 2, seg = (t & 3) * 8;
            uint4 vv = *(const uint4*)(vs_g + (rowbase + row) * DV + dc * 32 + seg);
            const u16* vp = (const u16*)&vv;
            float b_ = betaL[row];
#pragma unroll
            for (int j2 = 0; j2 < 8; j2++)
                vbL[row * 36 + seg + j2] = b_ * bf2f(vp[j2]);
        }
#pragma unroll
        for (int pass = 0; pass < 2; pass++) {
            int idx = t + pass * 256;            // 0..511
            int r = idx >> 2, c0 = (idx & 3) * 8;
#pragma unroll
            for (int i2 = 0; i2 < 8; i2++) {
                float x = S0L[r * 33 + c0 + i2];
                u16 hi = f2bf(x);
                float lo = x - bf2f(hi);
                s0hiT[(c0 + i2) * 136 + r] = hi;
                s0loT[(c0 + i2) * 136 + r] = f2bf(lo);
            }
        }
        __syncthreads();

        // ---- b: RHS (64x32) -> rhsT bf16 ----
        {
            int ti = w;
#pragma unroll
            for (int tj = 0; tj < 2; tj++) {
                float4v acc;
#pragma unroll
                for (int r = 0; r < 4; r++)
                    acc[r] = vbL[(ti * 16 + quad * 4 + r) * 36 + tj * 16 + l15];
#pragma unroll
                for (int k0 = 0; k0 < 128; k0 += 32) {
                    FragU a, bh_, bl_;
                    a.u  = *(const uint4*)&wbL[(ti * 16 + l15) * 136 + k0 + quad * 8];
                    bh_.u = *(const uint4*)&s0hiT[(tj * 16 + l15) * 136 + k0 + quad * 8];
                    acc = __builtin_amdgcn_mfma_f32_16x16x32_bf16(a.v, bh_.v, acc, 0, 0, 0);
                    bl_.u = *(const uint4*)&s0loT[(tj * 16 + l15) * 136 + k0 + quad * 8];
                    acc = __builtin_amdgcn_mfma_f32_16x16x32_bf16(a.v, bl_.v, acc, 0, 0, 0);
                }
                int n = tj * 16 + l15, m = ti * 16 + quad * 4;
                u16 tmp[4] = {f2bf(acc[0]), f2bf(acc[1]), f2bf(acc[2]), f2bf(acc[3])};
                *(uint2*)&rhsT[n * 72 + m] = *(uint2*)tmp;
            }
        }
        __syncthreads();

        // ---- c: D = T*RHS (64x32) -> DT bf16 ----
        {
            int ti = w;
#pragma unroll
            for (int tj = 0; tj < 2; tj++) {
                float4v acc = (float4v){0.f, 0.f, 0.f, 0.f};
#pragma unroll
                for (int k0 = 0; k0 < 64; k0 += 32) {
                    FragU a, b_;
                    a.u = *(const uint4*)&TL[(ti * 16 + l15) * 72 + k0 + quad * 8];
                    b_.u = *(const uint4*)&rhsT[(tj * 16 + l15) * 72 + k0 + quad * 8];
                    acc = __builtin_amdgcn_mfma_f32_16x16x32_bf16(a.v, b_.v, acc, 0, 0, 0);
                }
                int n = tj * 16 + l15, m = ti * 16 + quad * 4;
                u16 tmp[4] = {f2bf(acc[0]), f2bf(acc[1]), f2bf(acc[2]), f2bf(acc[3])};
                *(uint2*)&DT[n * 72 + m] = *(uint2*)tmp;
            }
        }
        __syncthreads();

        // ---- d: O = ql*S0 + P*D ; S0 = gam*S0 + kdT*D ----
        {
            int ti = w;
#pragma unroll
            for (int tj = 0; tj < 2; tj++) {
                float4v acc = (float4v){0.f, 0.f, 0.f, 0.f};
#pragma unroll
                for (int k0 = 0; k0 < 128; k0 += 32) {
                    FragU a, bh_, bl_;
                    a.u = *(const uint4*)&qlL[(ti * 16 + l15) * 136 + k0 + quad * 8];
                    bh_.u = *(const uint4*)&s0hiT[(tj * 16 + l15) * 136 + k0 + quad * 8];
                    acc = __builtin_amdgcn_mfma_f32_16x16x32_bf16(a.v, bh_.v, acc, 0, 0, 0);
                    bl_.u = *(const uint4*)&s0loT[(tj * 16 + l15) * 136 + k0 + quad * 8];
                    acc = __builtin_amdgcn_mfma_f32_16x16x32_bf16(a.v, bl_.v, acc, 0, 0, 0);
                }
#pragma unroll
                for (int k0 = 0; k0 < 64; k0 += 32) {
                    FragU a, b_;
                    a.u = *(const uint4*)&PL[(ti * 16 + l15) * 72 + k0 + quad * 8];
                    b_.u = *(const uint4*)&DT[(tj * 16 + l15) * 72 + k0 + quad * 8];
                    acc = __builtin_amdgcn_mfma_f32_16x16x32_bf16(a.v, b_.v, acc, 0, 0, 0);
                }
#pragma unroll
                for (int r = 0; r < 4; r++)
                    Obuf[(ti * 16 + quad * 4 + r) * 36 + tj * 16 + l15] = acc[r];
            }
#pragma unroll
            for (int s2 = 0; s2 < 2; s2++) {
                int ti = w * 2 + s2;
#pragma unroll
                for (int tj = 0; tj < 2; tj++) {
                    float4v acc = (float4v){0.f, 0.f, 0.f, 0.f};
#pragma unroll
                    for (int k0 = 0; k0 < 64; k0 += 32) {
                        FragU a, b_;
                        a.u = *(const uint4*)&kdT[(ti * 16 + l15) * 72 + k0 + quad * 8];
                        b_.u = *(const uint4*)&DT[(tj * 16 + l15) * 72 + k0 + quad * 8];
                        acc = __builtin_amdgcn_mfma_f32_16x16x32_bf16(a.v, b_.v, acc, 0, 0, 0);
                    }
#pragma unroll
                    for (int r = 0; r < 4; r++) {
                        int idx = (ti * 16 + quad * 4 + r) * 33 + tj * 16 + l15;
                        S0L[idx] = gamL * S0L[idx] + acc[r];
                    }
                }
            }
        }
        __syncthreads();

        // ---- e: store O (coalesced) ----
        {
            int r = t >> 2, c0 = (t & 3) * 8;
            float4 a  = *(const float4*)&Obuf[r * 36 + c0];
            float4 b2 = *(const float4*)&Obuf[r * 36 + c0 + 4];
            float* dst = o_g + ((bl + ts0 + r) * 16 + h) * 128L + dc * 32 + c0;
            *(float4*)dst = a;
            *(float4*)(dst + 4) = b2;
        }
        __syncthreads();
    }
}

// ---------------- gated RMS norm -> bf16 A2 ----------------------------------
__global__ __launch_bounds__(128) void gated_norm(
    const float* __restrict__ o, const u16* __restrict__ qkvz,
    const float* __restrict__ norm_w, u16* __restrict__ A2) {
    int bid = blockIdx.x;  // (b*L+l)*16 + h
    int t = threadIdx.x;   // 0..127
    float ov = o[(long)bid * 128 + t];
    float s = ov * ov;
#pragma unroll
    for (int off = 32; off > 0; off >>= 1) s += __shfl_down(s, off);
    __shared__ float ws2[2];
    if ((t & 63) == 0) ws2[t >> 6] = s;
    __syncthreads();
    float tot = ws2[0] + ws2[1];
    float rinv = rsqrtf(tot * (1.f / 128.f) + 1e-6f);
    int bl = bid >> 4, h = bid & 15;
    float z = bf2f(qkvz[(long)bl * NQKVZ + CONV_DIM + h * 128 + t]);
    float sig = 1.f / (1.f + expf(-z));
    float val = ov * rinv * norm_w[t] * sig;
    A2[(long)bl * 2048 + h * 128 + t] = f2bf(val);
}

// ---------------- host-side launcher -----------------------------------------
extern "C" void kernel_launch(void* const* d_in, const int* in_sizes, int n_in,
                              void* d_out, int out_size, void* d_ws, size_t ws_size,
                              hipStream_t stream) {
    const float* hs    = (const float*)d_in[0];
    const float* Wqkvz = (const float*)d_in[1];
    const float* Wba   = (const float*)d_in[2];
    const float* convw = (const float*)d_in[3];
    const float* convb = (const float*)d_in[4];
    const float* A_log = (const float*)d_in[5];
    const float* dtb   = (const float*)d_in[6];
    const float* normw = (const float*)d_in[7];
    const float* Wout  = (const float*)d_in[8];

    char* ws = (char*)d_ws;
    size_t off = 0;
    auto alloc = [&](size_t bytes) {
        size_t o = off;
        off = (off + bytes + 255) & ~(size_t)255;
        return o;
    };
    // region0: WqkvzT (bf16, 33.5MB) — dead after GEMM1, reused for os (fp32)
    size_t r0 = alloc((size_t)NQKVZ * HID * 2);
    // region1: hs_bf16 (16.8MB) — dead after GEMM1, reused for A2 (bf16)
    size_t r1 = alloc((size_t)4096 * HID * 2);
    u16*   WqkvzT = (u16*)(ws + r0);
    float* os     = (float*)(ws + r0);
    u16*   hsb    = (u16*)(ws + r1);
    u16*   A2     = (u16*)(ws + r1);
    u16*   qkvz   = (u16*)(ws + alloc((size_t)4096 * NQKVZ * 2));
    u16*   qs     = (u16*)(ws + alloc((size_t)64 * L_SEQ * DK * 2));
    u16*   ks     = (u16*)(ws + alloc((size_t)64 * L_SEQ * DK * 2));
    u16*   vs     = (u16*)(ws + alloc((size_t)64 * L_SEQ * DV * 2));
    float* gs     = (float*)(ws + alloc((size_t)64 * L_SEQ * 4));
    float* bs     = (float*)(ws + alloc((size_t)64 * L_SEQ * 4));
    u16*   WoutT  = (u16*)(ws + alloc((size_t)HID * 2048 * 2));
    float* WbaT   = (float*)(ws + alloc((size_t)32 * HID * 4));
    u16*   Tbuf   = (u16*)(ws + alloc((size_t)1024 * 4096 * 2));
    u16*   Pbuf   = (u16*)(ws + alloc((size_t)1024 * 4096 * 2));
    float* lamb   = (float*)(ws + alloc((size_t)1024 * 64 * 4));
    float* dlb    = (float*)(ws + alloc((size_t)1024 * 64 * 4));
    float* gamb   = (float*)(ws + alloc((size_t)1024 * 4));

    // 1. convert + transposes
    hipLaunchKernelGGL(f32_to_bf16, dim3(4096), dim3(256), 0, stream, hs, hsb);
    hipLaunchKernelGGL(transpose_f32_bf16, dim3(NQKVZ / 32, HID / 32), dim3(256), 0, stream,
                       Wqkvz, WqkvzT, HID, NQKVZ);
    hipLaunchKernelGGL(transpose_f32_bf16, dim3(2048 / 32, 2048 / 32), dim3(256), 0, stream,
                       Wout, WoutT, 2048, 2048);
    hipLaunchKernelGGL(transpose_f32_f32, dim3(1, HID / 32), dim3(256), 0, stream,
                       Wba, WbaT, HID, 32);

    // 2. GEMM1: qkvz = hs @ W_qkvz
    hipLaunchKernelGGL((gemm_abT<u16>), dim3(NQKVZ / BN, 4096 / BM), dim3(256), 0, stream,
                       hsb, WqkvzT, qkvz, 4096, NQKVZ, HID);

    // 3. ba -> g, beta
    hipLaunchKernelGGL(ba_kernel, dim3(4096), dim3(64), 0, stream,
                       hs, WbaT, A_log, dtb, gs, bs);

    // 4. conv + l2norm -> q,k,v (bf16)
    hipLaunchKernelGGL(conv_qkv, dim3(4096), dim3(256), 0, stream,
                       qkvz, convw, convb, qs, ks, vs);

    // 5a. chunk prep (parallel): T, P, decay scalars
    hipLaunchKernelGGL(gdn_prep, dim3(1024), dim3(256), 0, stream,
                       ks, qs, gs, bs, Tbuf, Pbuf, lamb, dlb, gamb);

    // 5b. chunk recurrence (MFMA)
    hipLaunchKernelGGL(gdn_chunk, dim3(256), dim3(256), 0, stream,
                       qs, ks, vs, bs, Tbuf, Pbuf, lamb, dlb, gamb, os);

    // 6. gated RMS norm -> bf16 A2
    hipLaunchKernelGGL(gated_norm, dim3(4096 * NH), dim3(128), 0, stream,
                       os, qkvz, normw, A2);

    // 7. GEMM2: out = A2 @ W_out
    hipLaunchKernelGGL((gemm_abT<float>), dim3(2048 / BN, 4096 / BM), dim3(256), 0, stream,
                       A2, WoutT, (float*)d_out, 4096, 2048, HID);
}

// Round 8
// 790.932 us; speedup vs baseline: 1.1816x; 1.0155x over previous
//
#include <hip/hip_runtime.h>

typedef unsigned short u16;
typedef unsigned int u32;
typedef short short8 __attribute__((ext_vector_type(8)));
typedef float float4v __attribute__((ext_vector_type(4)));

#define L_SEQ 1024
#define NB 4
#define NH 16
#define DK 128
#define DV 128
#define HID 2048
#define NQKVZ 8192
#define CONV_DIM 6144
#define GDN_SCALE 0.08838834764831845f  // 128^-0.5

static __device__ __forceinline__ float bf2f(u16 u) {
    union { u32 i; float f; } x; x.i = ((u32)u) << 16; return x.f;
}
static __device__ __forceinline__ u16 f2bf(float f) {
    union { float f; u32 u; } x; x.f = f;
    u32 r = x.u + 0x7FFF + ((x.u >> 16) & 1);
    return (u16)(r >> 16);
}

union FragU { short8 v; uint4 u; };

// async global->LDS, 16B per lane (lane-contiguous LDS dest required).
#define GLOAD_LDS16(g, l)                                        \
    __builtin_amdgcn_global_load_lds(                            \
        (const __attribute__((address_space(1))) void*)(g),      \
        (__attribute__((address_space(3))) void*)(l), 16, 0, 0)

// ---------------- fp32 -> bf16 elementwise convert ---------------------------
__global__ __launch_bounds__(256) void f32_to_bf16(
    const float* __restrict__ in, u16* __restrict__ out) {
    long i = ((long)blockIdx.x * 256 + threadIdx.x) * 8;
    float4 a = *(const float4*)(in + i);
    float4 b = *(const float4*)(in + i + 4);
    u16 tmp[8];
    tmp[0] = f2bf(a.x); tmp[1] = f2bf(a.y); tmp[2] = f2bf(a.z); tmp[3] = f2bf(a.w);
    tmp[4] = f2bf(b.x); tmp[5] = f2bf(b.y); tmp[6] = f2bf(b.z); tmp[7] = f2bf(b.w);
    *(uint4*)(out + i) = *(const uint4*)tmp;
}

// ---------------- transpose fp32 (RxC) -> bf16 (CxR) -------------------------
__global__ __launch_bounds__(256) void transpose_f32_bf16(
    const float* __restrict__ in, u16* __restrict__ out, int R, int C) {
    __shared__ float tile[32][33];
    int bx = blockIdx.x, by = blockIdx.y;
    int c = threadIdx.x & 31;
    int r0 = threadIdx.x >> 5;
#pragma unroll
    for (int i = 0; i < 4; i++) {
        int r = r0 + i * 8;
        tile[r][c] = in[(long)(by * 32 + r) * C + bx * 32 + c];
    }
    __syncthreads();
#pragma unroll
    for (int i = 0; i < 4; i++) {
        int r = r0 + i * 8;
        out[(long)(bx * 32 + r) * R + by * 32 + c] = f2bf(tile[c][r]);
    }
}

// ---------------- transpose fp32 (RxC) -> fp32 (CxR) -------------------------
__global__ __launch_bounds__(256) void transpose_f32_f32(
    const float* __restrict__ in, float* __restrict__ out, int R, int C) {
    __shared__ float tile[32][33];
    int bx = blockIdx.x, by = blockIdx.y;
    int c = threadIdx.x & 31;
    int r0 = threadIdx.x >> 5;
#pragma unroll
    for (int i = 0; i < 4; i++) {
        int r = r0 + i * 8;
        tile[r][c] = in[(long)(by * 32 + r) * C + bx * 32 + c];
    }
    __syncthreads();
#pragma unroll
    for (int i = 0; i < 4; i++) {
        int r = r0 + i * 8;
        out[(long)(bx * 32 + r) * R + by * 32 + c] = tile[c][r];
    }
}

// ---------------- GEMM (m97 structure): C = A * BT^T, bf16 in, OutT out ------
#define BM 128
#define BN 128
#define BKK 32

static __device__ __forceinline__ void store_out(u16* p, float v)  { *p = f2bf(v); }
static __device__ __forceinline__ void store_out(float* p, float v){ *p = v; }

template <typename OutT>
__global__ __launch_bounds__(256) void gemm_abT(
    const u16* __restrict__ A, const u16* __restrict__ BT,
    OutT* __restrict__ C, int M, int N, int K) {
    __shared__ u16 As[BM * BKK];
    __shared__ u16 Bs[BN * BKK];
    int t = threadIdx.x;
    int lane = t & 63;
    int w = t >> 6;
    int wm = (w & 1) * 64;
    int wn = (w >> 1) * 64;
    int l15 = lane & 15;
    int quad = lane >> 4;
    long blockM = (long)blockIdx.y * BM;
    long blockN = (long)blockIdx.x * BN;

    float4v acc[4][4];
#pragma unroll
    for (int i = 0; i < 4; i++)
#pragma unroll
        for (int j = 0; j < 4; j++) acc[i][j] = (float4v){0.f, 0.f, 0.f, 0.f};

    const u16* Ab = A + blockM * K;
    const u16* Bb = BT + blockN * K;

    const int r0 = t >> 2,         c0 = (t & 3) * 8;
    const int r1 = (t + 256) >> 2, c1 = ((t + 256) & 3) * 8;
    u16* As0 = As + t * 8;         u16* As1 = As + (t + 256) * 8;
    u16* Bs0 = Bs + t * 8;         u16* Bs1 = Bs + (t + 256) * 8;
    const u16* Ag0 = Ab + (long)r0 * K + c0;
    const u16* Ag1 = Ab + (long)r1 * K + c1;
    const u16* Bg0 = Bb + (long)r0 * K + c0;
    const u16* Bg1 = Bb + (long)r1 * K + c1;

    for (int k0 = 0; k0 < K; k0 += BKK) {
        __syncthreads();
        GLOAD_LDS16(Ag0 + k0, As0);
        GLOAD_LDS16(Ag1 + k0, As1);
        GLOAD_LDS16(Bg0 + k0, Bs0);
        GLOAD_LDS16(Bg1 + k0, Bs1);
        __syncthreads();

        FragU fa[4], fb[4];
#pragma unroll
        for (int i = 0; i < 4; i++) {
            fa[i].u = *(const uint4*)(As + (wm + i * 16 + l15) * BKK + quad * 8);
            fb[i].u = *(const uint4*)(Bs + (wn + i * 16 + l15) * BKK + quad * 8);
        }
#pragma unroll
        for (int i = 0; i < 4; i++)
#pragma unroll
            for (int j = 0; j < 4; j++)
                acc[i][j] = __builtin_amdgcn_mfma_f32_16x16x32_bf16(
                    fa[i].v, fb[j].v, acc[i][j], 0, 0, 0);
    }

#pragma unroll
    for (int i = 0; i < 4; i++) {
        long mrow = blockM + wm + i * 16 + quad * 4;
#pragma unroll
        for (int j = 0; j < 4; j++) {
            long col = blockN + wn + j * 16 + l15;
#pragma unroll
            for (int r = 0; r < 4; r++) {
                store_out(&C[(mrow + r) * N + col], acc[i][j][r]);
            }
        }
    }
}

// ---------------- ba: g raw, beta = sigmoid(b) -------------------------------
__global__ __launch_bounds__(64) void ba_kernel(
    const float* __restrict__ hs, const float* __restrict__ WbaT,
    const float* __restrict__ A_log, const float* __restrict__ dt_bias,
    float* __restrict__ gout, float* __restrict__ bout) {
    int bl = blockIdx.x;  // b*L + l
    int b = bl >> 10, l = bl & 1023;
    int t = threadIdx.x;
    __shared__ __align__(16) float hb[HID];
    const float* hrow = hs + (long)bl * HID;
#pragma unroll
    for (int i = 0; i < 8; i++) {
        int idx = (t + i * 64) * 4;
        *(float4*)(hb + idx) = *(const float4*)(hrow + idx);
    }
    __syncthreads();
    int n = t & 31, hf = t >> 5;
    const float* wrow = WbaT + (long)n * HID + hf * 1024;
    const float* hp = hb + hf * 1024;
    float acc = 0.f;
    for (int i = 0; i < 1024; i += 4) {
        float4 wv = *(const float4*)(wrow + i);
        float4 hv = *(const float4*)(hp + i);
        acc += wv.x * hv.x + wv.y * hv.y + wv.z * hv.z + wv.w * hv.w;
    }
    acc += __shfl_down(acc, 32);
    if (t < 32) {
        if (n < 16) {
            bout[((long)(b * NH + n)) * L_SEQ + l] = 1.f / (1.f + expf(-acc));
        } else {
            int h = n - 16;
            float x = acc + dt_bias[h];
            float sp = (x > 20.f) ? x : log1pf(expf(x));
            gout[((long)(b * NH + h)) * L_SEQ + l] = -expf(A_log[h]) * sp;
        }
    }
}

// ---------------- conv(KS=4) + l2norm(q,k) + split v -> bf16 -----------------
__global__ __launch_bounds__(256) void conv_qkv(
    const u16* __restrict__ qkvz, const float* __restrict__ conv_w,
    const float* __restrict__ conv_b,
    u16* __restrict__ qs, u16* __restrict__ ks, u16* __restrict__ vs) {
    int bl = blockIdx.x;  // b*L + l
    int b = bl >> 10, l = bl & 1023;
    int t = threadIdx.x;
    __shared__ float xb[CONV_DIM];
    __shared__ float red[32][9];
    __shared__ float rbuf[32];

    for (int c = t; c < CONV_DIM; c += 256) {
        float acc = conv_b[c];
        float w0 = conv_w[c * 4 + 0];
        float w1 = conv_w[c * 4 + 1];
        float w2 = conv_w[c * 4 + 2];
        float w3 = conv_w[c * 4 + 3];
        long rowbase = (long)(b * L_SEQ) * NQKVZ + c;
        if (l - 3 >= 0) acc += bf2f(qkvz[rowbase + (long)(l - 3) * NQKVZ]) * w0;
        if (l - 2 >= 0) acc += bf2f(qkvz[rowbase + (long)(l - 2) * NQKVZ]) * w1;
        if (l - 1 >= 0) acc += bf2f(qkvz[rowbase + (long)(l - 1) * NQKVZ]) * w2;
        acc += bf2f(qkvz[rowbase + (long)l * NQKVZ]) * w3;
        xb[c] = acc;
    }
    __syncthreads();
    {
        int grp = t >> 3;
        int j8 = t & 7;
        float s = 0.f;
#pragma unroll
        for (int i = 0; i < 16; i++) {
            float xv = xb[grp * 128 + j8 * 16 + i];
            s += xv * xv;
        }
        red[grp][j8] = s;
    }
    __syncthreads();
    if (t < 32) {
        float s = 0.f;
#pragma unroll
        for (int i = 0; i < 8; i++) s += red[t][i];
        rbuf[t] = rsqrtf(s + 1e-6f);
    }
    __syncthreads();
    for (int c = t; c < CONV_DIM; c += 256) {
        float xv = xb[c];
        if (c < 2048) {
            int h = c >> 7, d = c & 127;
            qs[(((long)(b * NH + h)) * L_SEQ + l) * DK + d] = f2bf(xv * rbuf[h]);
        } else if (c < 4096) {
            int c2 = c - 2048;
            int h = c2 >> 7, d = c2 & 127;
            ks[(((long)(b * NH + h)) * L_SEQ + l) * DK + d] = f2bf(xv * rbuf[16 + h]);
        } else {
            int c2 = c - 4096;
            int h = c2 >> 7, d = c2 & 127;
            vs[(((long)(b * NH + h)) * L_SEQ + l) * DV + d] = f2bf(xv);
        }
    }
}

// ---------------- gdn_prep: per-chunk T, P, wb, ql, kd, gam (parallel) -------
// 1024 blocks = (bh=64) x (chunk=16); 256 threads (4 waves).
// A[t][j] = beta_t e^{G_t-G_j}(k_t.k_j) (j<t); T = (I+A)^{-1} (fwd subst);
// P[t][j] = scale e^{G_t-G_j}(q_t.k_j) (j<=t).
// wbq[t][k] = -beta_t lam_t k ; qlq[t][k] = scale lam_t q ; kdq[k][t] = dl_t k.
__global__ __launch_bounds__(256) void gdn_prep(
    const u16* __restrict__ ks_g, const u16* __restrict__ qs_g,
    const float* __restrict__ g_g, const float* __restrict__ b_g,
    u16* __restrict__ Tbuf, u16* __restrict__ Pbuf,
    u16* __restrict__ wbq, u16* __restrict__ qlq, u16* __restrict__ kdq,
    float* __restrict__ gam_g) {
    int cid = blockIdx.x;
    int bh = cid >> 4;
    int ch = cid & 15;
    long rowbase = (long)bh * L_SEQ + ch * 64;
    int t = threadIdx.x;
    int lane = t & 63, w = t >> 6, l15 = lane & 15, quad = lane >> 4;

    __shared__ u16 Kl[64 * 136];
    __shared__ u16 Ql[64 * 136];
    __shared__ float Am[64 * 66];
    __shared__ float Tm[64 * 66];
    __shared__ float Gs[64], lamL[64], betaL[64], dlL[64];

    {   // stage K,Q rows bf16 -> padded LDS; stage g, beta
        int row = t >> 2, seg = (t & 3) * 32;
        const u16* ksrc = ks_g + (rowbase + row) * DK + seg;
        const u16* qsrc = qs_g + (rowbase + row) * DK + seg;
        *(uint4*)&Kl[row * 136 + seg]      = *(const uint4*)ksrc;
        *(uint4*)&Kl[row * 136 + seg + 8]  = *(const uint4*)(ksrc + 8);
        *(uint4*)&Kl[row * 136 + seg + 16] = *(const uint4*)(ksrc + 16);
        *(uint4*)&Kl[row * 136 + seg + 24] = *(const uint4*)(ksrc + 24);
        *(uint4*)&Ql[row * 136 + seg]      = *(const uint4*)qsrc;
        *(uint4*)&Ql[row * 136 + seg + 8]  = *(const uint4*)(qsrc + 8);
        *(uint4*)&Ql[row * 136 + seg + 16] = *(const uint4*)(qsrc + 16);
        *(uint4*)&Ql[row * 136 + seg + 24] = *(const uint4*)(qsrc + 24);
        if (t < 64) Gs[t] = g_g[rowbase + t];
        else if (t < 128) betaL[t - 64] = b_g[rowbase + t - 64];
    }
    __syncthreads();
    if (t == 0) {   // inclusive prefix sum of g
        float run = 0.f;
        for (int i = 0; i < 64; i++) { run += Gs[i]; Gs[i] = run; }
    }
    __syncthreads();
    if (t < 64) {
        float G63 = Gs[63];
        float lm = expf(Gs[t]);
        lamL[t] = lm;
        dlL[t] = expf(G63 - Gs[t]);
        if (t == 0) gam_g[cid] = expf(G63);
    }
    // MFMA: KK^T and QK^T (wave w = row-stripe w*16)
    float4v accKK[4], accQK[4];
#pragma unroll
    for (int tj = 0; tj < 4; tj++) {
        accKK[tj] = (float4v){0.f, 0.f, 0.f, 0.f};
        accQK[tj] = (float4v){0.f, 0.f, 0.f, 0.f};
    }
#pragma unroll
    for (int k0 = 0; k0 < 128; k0 += 32) {
        FragU ka, qa;
        ka.u = *(const uint4*)&Kl[(w * 16 + l15) * 136 + k0 + quad * 8];
        qa.u = *(const uint4*)&Ql[(w * 16 + l15) * 136 + k0 + quad * 8];
#pragma unroll
        for (int tj = 0; tj < 4; tj++) {
            FragU kb;
            kb.u = *(const uint4*)&Kl[(tj * 16 + l15) * 136 + k0 + quad * 8];
            accKK[tj] = __builtin_amdgcn_mfma_f32_16x16x32_bf16(ka.v, kb.v, accKK[tj], 0, 0, 0);
            accQK[tj] = __builtin_amdgcn_mfma_f32_16x16x32_bf16(qa.v, kb.v, accQK[tj], 0, 0, 0);
        }
    }
    __syncthreads();   // lamL/betaL/dlL visible to all
    // mask + scale; Am -> LDS fp32, P -> global bf16
#pragma unroll
    for (int tj = 0; tj < 4; tj++) {
#pragma unroll
        for (int r = 0; r < 4; r++) {
            int ti_ = w * 16 + quad * 4 + r;
            int j = tj * 16 + l15;
            float e = (j <= ti_) ? expf(Gs[ti_] - Gs[j]) : 0.f;
            Am[ti_ * 66 + j] = (j < ti_) ? betaL[ti_] * e * accKK[tj][r] : 0.f;
            Pbuf[(long)cid * 4096 + ti_ * 64 + j] =
                (j <= ti_) ? f2bf(GDN_SCALE * e * accQK[tj][r]) : (u16)0;
        }
    }
    // wbq, qlq (row-major [64][128])
    {
        int row = t >> 2, seg = (t & 3) * 32;
        float sw = -betaL[row] * lamL[row];
        float sq = GDN_SCALE * lamL[row];
#pragma unroll
        for (int c0 = 0; c0 < 32; c0 += 8) {
            u16 wt[8], qt2[8];
#pragma unroll
            for (int j2 = 0; j2 < 8; j2++) {
                wt[j2]  = f2bf(sw * bf2f(Kl[row * 136 + seg + c0 + j2]));
                qt2[j2] = f2bf(sq * bf2f(Ql[row * 136 + seg + c0 + j2]));
            }
            *(uint4*)&wbq[(long)cid * 8192 + row * 128 + seg + c0] = *(uint4*)wt;
            *(uint4*)&qlq[(long)cid * 8192 + row * 128 + seg + c0] = *(uint4*)qt2;
        }
    }
    // kdq (transposed [128 k][64 t])
    if (t < 128) {
#pragma unroll
        for (int t0 = 0; t0 < 64; t0 += 8) {
            u16 tmp[8];
#pragma unroll
            for (int j2 = 0; j2 < 8; j2++)
                tmp[j2] = f2bf(dlL[t0 + j2] * bf2f(Kl[(t0 + j2) * 136 + t]));
            *(uint4*)&kdq[(long)cid * 8192 + t * 64 + t0] = *(uint4*)tmp;
        }
    }
    __syncthreads();
    // forward substitution: column t independent per lane (wave 0 only)
    if (t < 64) {
        Tm[t] = (t == 0) ? 1.f : 0.f;
        for (int i = 1; i < 64; i++) {
            float s = (i == t) ? 1.f : 0.f;
            for (int j = 0; j < i; j++)
                s -= Am[i * 66 + j] * Tm[j * 66 + t];
            Tm[i * 66 + t] = s;
        }
    }
    __syncthreads();
    {   // T -> global bf16
        int row = t >> 2, c0 = (t & 3) * 16;
        u16 tmp[16];
#pragma unroll
        for (int i = 0; i < 16; i++) tmp[i] = f2bf(Tm[row * 66 + c0 + i]);
        *(uint4*)&Tbuf[(long)cid * 4096 + row * 64 + c0]     = *(uint4*)tmp;
        *(uint4*)&Tbuf[(long)cid * 4096 + row * 64 + c0 + 8] = *(uint4*)(tmp + 8);
    }
}

// ---------------- gdn_chunk v2: sequential chunk recurrence (MFMA) -----------
// 256 blocks = (bh=64) x (dc=4: 32 v-cols). 256 threads (4 waves).
// All bf16 tiles staged via global_load_lds w/ XOR chunk-swizzle
// (slot = r*CH + (cc ^ (r&7)) -> 2-way free fragment banks).
// S0^T lives in registers (C-layout): wave w owns k-tiles {2w,2w+1} x v-tiles
// {0,1}. Update: S0' = mfma(D^T, kd, gam*S0). Phases: a(stage+split) b(RHS)
// c(D=T*RHS) d(O + S0 update) — 4 barriers/chunk.
__global__ __launch_bounds__(256) void gdn_chunk(
    const u16* __restrict__ vs_g, const float* __restrict__ b_g,
    const u16* __restrict__ Tq, const u16* __restrict__ Pq,
    const u16* __restrict__ wbq, const u16* __restrict__ qlq,
    const u16* __restrict__ kdq, const float* __restrict__ gam_g,
    float* __restrict__ o_g) {
    int bid = blockIdx.x;
    int dc = bid & 3;
    int bh = bid >> 2;
    int b = bid >> 6, h = bh & 15;
    int t = threadIdx.x;
    int lane = t & 63, w = t >> 6, l15 = lane & 15, quad = lane >> 4;

    __shared__ u16 TL[64 * 64];     // swizzled, 8 chunks/row
    __shared__ u16 PL[64 * 64];
    __shared__ u16 wbL[64 * 128];   // swizzled, 16 chunks/row
    __shared__ u16 qlL[64 * 128];
    __shared__ u16 kdL[128 * 64];   // swizzled, 8 chunks/row
    __shared__ u16 s0h[32 * 136], s0l[32 * 136];   // S0^T [v][k] hi/lo
    __shared__ float vOb[64 * 36];  // vb (phases a,b) aliased with Obuf (d,e)
    __shared__ u16 rhsT[32 * 72], DT[32 * 72];

    float4v S0r[2][2];  // [vt][kt_local]; wave w: k-tiles 2w+ktl
#pragma unroll
    for (int i = 0; i < 2; i++)
#pragma unroll
        for (int j = 0; j < 2; j++) S0r[i][j] = (float4v){0.f, 0.f, 0.f, 0.f};

    const int vrow = t >> 2, vseg = (t & 3) * 8;   // vb / O-store mapping

    for (int ch = 0; ch < 16; ch++) {
        int cid = bh * 16 + ch;
        long rowbase = (long)bh * L_SEQ + ch * 64;
        float gam = gam_g[cid];

        // ================= phase a =================
        // store previous chunk's O (reads vOb slots this thread then overwrites)
        if (ch > 0) {
            float4 a  = *(const float4*)&vOb[vrow * 36 + vseg];
            float4 b2 = *(const float4*)&vOb[vrow * 36 + vseg + 4];
            float* dst = o_g + (((long)bh * L_SEQ + (ch - 1) * 64 + vrow) % L_SEQ
                                + (long)b * L_SEQ) * 0;  // (placeholder, replaced below)
            (void)dst;
            float* d2 = o_g + ((((long)b * L_SEQ) + (ch - 1) * 64 + vrow) * 16 + h) * 128L
                        + dc * 32 + vseg;
            *(float4*)d2 = a;
            *(float4*)(d2 + 4) = b2;
        }
        // vb = beta * v   (same slots as the O just stored — per-thread ordered)
        {
            float beta = b_g[rowbase + vrow];
            uint4 vv = *(const uint4*)(vs_g + (rowbase + vrow) * DV + dc * 32 + vseg);
            const u16* vp = (const u16*)&vv;
#pragma unroll
            for (int j2 = 0; j2 < 8; j2++)
                vOb[vrow * 36 + vseg + j2] = beta * bf2f(vp[j2]);
        }
        // S0 hi/lo split from registers
#pragma unroll
        for (int vt = 0; vt < 2; vt++)
#pragma unroll
            for (int ktl = 0; ktl < 2; ktl++) {
                int kcol = (2 * w + ktl) * 16 + l15;
#pragma unroll
                for (int r = 0; r < 4; r++) {
                    float x = S0r[vt][ktl][r];
                    u16 hi = f2bf(x);
                    float lo = x - bf2f(hi);
                    int v = vt * 16 + quad * 4 + r;
                    s0h[v * 136 + kcol] = hi;
                    s0l[v * 136 + kcol] = f2bf(lo);
                }
            }
        // async stage: T, P (512 slots each), wb, ql (1024), kd (1024)
#pragma unroll
        for (int p = 0; p < 2; p++) {
            int sl = t + p * 256;
            int r = sl >> 3, cg = (sl & 7) ^ (r & 7);
            GLOAD_LDS16(Tq + (long)cid * 4096 + r * 64 + cg * 8, TL + sl * 8);
            GLOAD_LDS16(Pq + (long)cid * 4096 + r * 64 + cg * 8, PL + sl * 8);
        }
#pragma unroll
        for (int p = 0; p < 4; p++) {
            int sl = t + p * 256;
            int r16 = sl >> 4, cg16 = (sl & 15) ^ (r16 & 7);
            GLOAD_LDS16(wbq + (long)cid * 8192 + r16 * 128 + cg16 * 8, wbL + sl * 8);
            GLOAD_LDS16(qlq + (long)cid * 8192 + r16 * 128 + cg16 * 8, qlL + sl * 8);
            int r8 = sl >> 3, cg8 = (sl & 7) ^ (r8 & 7);
            GLOAD_LDS16(kdq + (long)cid * 8192 + r8 * 64 + cg8 * 8, kdL + sl * 8);
        }
        __syncthreads();

        // ================= phase b: RHS = vb + wb*(S0h+S0l) -> rhsT ==========
        {
            int arow = w * 16 + l15;
#pragma unroll
            for (int tj = 0; tj < 2; tj++) {
                float4v acc;
#pragma unroll
                for (int r = 0; r < 4; r++)
                    acc[r] = vOb[(w * 16 + quad * 4 + r) * 36 + tj * 16 + l15];
#pragma unroll
                for (int k0 = 0; k0 < 128; k0 += 32) {
                    FragU a, bh_, bl_;
                    int sl = arow * 16 + (((k0 >> 3) + quad) ^ (arow & 7));
                    a.u = *(const uint4*)(wbL + sl * 8);
                    bh_.u = *(const uint4*)&s0h[(tj * 16 + l15) * 136 + k0 + quad * 8];
                    acc = __builtin_amdgcn_mfma_f32_16x16x32_bf16(a.v, bh_.v, acc, 0, 0, 0);
                    bl_.u = *(const uint4*)&s0l[(tj * 16 + l15) * 136 + k0 + quad * 8];
                    acc = __builtin_amdgcn_mfma_f32_16x16x32_bf16(a.v, bl_.v, acc, 0, 0, 0);
                }
                int n = tj * 16 + l15, m = w * 16 + quad * 4;
                u16 tmp[4] = {f2bf(acc[0]), f2bf(acc[1]), f2bf(acc[2]), f2bf(acc[3])};
                *(uint2*)&rhsT[n * 72 + m] = *(uint2*)tmp;
            }
        }
        __syncthreads();

        // ================= phase c: D = T*RHS -> DT ==========================
        {
            int arow = w * 16 + l15;
#pragma unroll
            for (int tj = 0; tj < 2; tj++) {
                float4v acc = (float4v){0.f, 0.f, 0.f, 0.f};
#pragma unroll
                for (int k0 = 0; k0 < 64; k0 += 32) {
                    FragU a, b_;
                    int sl = arow * 8 + (((k0 >> 3) + quad) ^ (arow & 7));
                    a.u = *(const uint4*)(TL + sl * 8);
                    b_.u = *(const uint4*)&rhsT[(tj * 16 + l15) * 72 + k0 + quad * 8];
                    acc = __builtin_amdgcn_mfma_f32_16x16x32_bf16(a.v, b_.v, acc, 0, 0, 0);
                }
                int n = tj * 16 + l15, m = w * 16 + quad * 4;
                u16 tmp[4] = {f2bf(acc[0]), f2bf(acc[1]), f2bf(acc[2]), f2bf(acc[3])};
                *(uint2*)&DT[n * 72 + m] = *(uint2*)tmp;
            }
        }
        __syncthreads();

        // ================= phase d: O = ql*S0 + P*D ; S0 = gam*S0 + kd^T D ===
        {
            int arow = w * 16 + l15;
#pragma unroll
            for (int tj = 0; tj < 2; tj++) {
                float4v acc = (float4v){0.f, 0.f, 0.f, 0.f};
#pragma unroll
                for (int k0 = 0; k0 < 128; k0 += 32) {
                    FragU a, bh_, bl_;
                    int sl = arow * 16 + (((k0 >> 3) + quad) ^ (arow & 7));
                    a.u = *(const uint4*)(qlL + sl * 8);
                    bh_.u = *(const uint4*)&s0h[(tj * 16 + l15) * 136 + k0 + quad * 8];
                    acc = __builtin_amdgcn_mfma_f32_16x16x32_bf16(a.v, bh_.v, acc, 0, 0, 0);
                    bl_.u = *(const uint4*)&s0l[(tj * 16 + l15) * 136 + k0 + quad * 8];
                    acc = __builtin_amdgcn_mfma_f32_16x16x32_bf16(a.v, bl_.v, acc, 0, 0, 0);
                }
#pragma unroll
                for (int k0 = 0; k0 < 64; k0 += 32) {
                    FragU a, b_;
                    int sl = arow * 8 + (((k0 >> 3) + quad) ^ (arow & 7));
                    a.u = *(const uint4*)(PL + sl * 8);
                    b_.u = *(const uint4*)&DT[(tj * 16 + l15) * 72 + k0 + quad * 8];
                    acc = __builtin_amdgcn_mfma_f32_16x16x32_bf16(a.v, b_.v, acc, 0, 0, 0);
                }
#pragma unroll
                for (int r = 0; r < 4; r++)
                    vOb[(w * 16 + quad * 4 + r) * 36 + tj * 16 + l15] = acc[r];
            }
            // S0^T update: S0r[vt][ktl] = gam*S0r + DT(v,t) x kd(t,k)
#pragma unroll
            for (int vt = 0; vt < 2; vt++)
#pragma unroll
                for (int ktl = 0; ktl < 2; ktl++) {
                    int krow = (2 * w + ktl) * 16 + l15;
                    float4v acc = S0r[vt][ktl];
#pragma unroll
                    for (int r = 0; r < 4; r++) acc[r] *= gam;
#pragma unroll
                    for (int k0 = 0; k0 < 64; k0 += 32) {
                        FragU a, b_;
                        a.u = *(const uint4*)&DT[(vt * 16 + l15) * 72 + k0 + quad * 8];
                        int sl = krow * 8 + (((k0 >> 3) + quad) ^ (krow & 7));
                        b_.u = *(const uint4*)(kdL + sl * 8);
                        acc = __builtin_amdgcn_mfma_f32_16x16x32_bf16(a.v, b_.v, acc, 0, 0, 0);
                    }
                    S0r[vt][ktl] = acc;
                }
        }
        __syncthreads();
    }
    // final chunk's O store
    {
        float4 a  = *(const float4*)&vOb[vrow * 36 + vseg];
        float4 b2 = *(const float4*)&vOb[vrow * 36 + vseg + 4];
        float* d2 = o_g + ((((long)b * L_SEQ) + 15 * 64 + vrow) * 16 + h) * 128L
                    + dc * 32 + vseg;
        *(float4*)d2 = a;
        *(float4*)(d2 + 4) = b2;
    }
}

// ---------------- gated RMS norm -> bf16 A2 ----------------------------------
__global__ __launch_bounds__(128) void gated_norm(
    const float* __restrict__ o, const u16* __restrict__ qkvz,
    const float* __restrict__ norm_w, u16* __restrict__ A2) {
    int bid = blockIdx.x;  // (b*L+l)*16 + h
    int t = threadIdx.x;   // 0..127
    float ov = o[(long)bid * 128 + t];
    float s = ov * ov;
#pragma unroll
    for (int off = 32; off > 0; off >>= 1) s += __shfl_down(s, off);
    __shared__ float ws2[2];
    if ((t & 63) == 0) ws2[t >> 6] = s;
    __syncthreads();
    float tot = ws2[0] + ws2[1];
    float rinv = rsqrtf(tot * (1.f / 128.f) + 1e-6f);
    int bl = bid >> 4, h = bid & 15;
    float z = bf2f(qkvz[(long)bl * NQKVZ + CONV_DIM + h * 128 + t]);
    float sig = 1.f / (1.f + expf(-z));
    float val = ov * rinv * norm_w[t] * sig;
    A2[(long)bl * 2048 + h * 128 + t] = f2bf(val);
}

// ---------------- host-side launcher -----------------------------------------
extern "C" void kernel_launch(void* const* d_in, const int* in_sizes, int n_in,
                              void* d_out, int out_size, void* d_ws, size_t ws_size,
                              hipStream_t stream) {
    const float* hs    = (const float*)d_in[0];
    const float* Wqkvz = (const float*)d_in[1];
    const float* Wba   = (const float*)d_in[2];
    const float* convw = (const float*)d_in[3];
    const float* convb = (const float*)d_in[4];
    const float* A_log = (const float*)d_in[5];
    const float* dtb   = (const float*)d_in[6];
    const float* normw = (const float*)d_in[7];
    const float* Wout  = (const float*)d_in[8];

    char* ws = (char*)d_ws;
    size_t off = 0;
    auto alloc = [&](size_t bytes) {
        size_t o = off;
        off = (off + bytes + 255) & ~(size_t)255;
        return o;
    };
    // region0: WqkvzT (bf16) — dead after GEMM1, reused for os (fp32)
    size_t r0 = alloc((size_t)NQKVZ * HID * 2);
    // region1: hs_bf16 — dead after GEMM1, reused for A2 (bf16)
    size_t r1 = alloc((size_t)4096 * HID * 2);
    u16*   WqkvzT = (u16*)(ws + r0);
    float* os     = (float*)(ws + r0);
    u16*   hsb    = (u16*)(ws + r1);
    u16*   A2     = (u16*)(ws + r1);
    u16*   qkvz   = (u16*)(ws + alloc((size_t)4096 * NQKVZ * 2));
    u16*   qs     = (u16*)(ws + alloc((size_t)64 * L_SEQ * DK * 2));
    u16*   ks     = (u16*)(ws + alloc((size_t)64 * L_SEQ * DK * 2));
    u16*   vs     = (u16*)(ws + alloc((size_t)64 * L_SEQ * DV * 2));
    float* gs     = (float*)(ws + alloc((size_t)64 * L_SEQ * 4));
    float* bs     = (float*)(ws + alloc((size_t)64 * L_SEQ * 4));
    u16*   WoutT  = (u16*)(ws + alloc((size_t)HID * 2048 * 2));
    float* WbaT   = (float*)(ws + alloc((size_t)32 * HID * 4));
    u16*   Tbuf   = (u16*)(ws + alloc((size_t)1024 * 4096 * 2));
    u16*   Pbuf   = (u16*)(ws + alloc((size_t)1024 * 4096 * 2));
    u16*   wbq    = (u16*)(ws + alloc((size_t)1024 * 8192 * 2));
    u16*   qlq    = (u16*)(ws + alloc((size_t)1024 * 8192 * 2));
    u16*   kdq    = (u16*)(ws + alloc((size_t)1024 * 8192 * 2));
    float* gamb   = (float*)(ws + alloc((size_t)1024 * 4));

    // 1. convert + transposes
    hipLaunchKernelGGL(f32_to_bf16, dim3(4096), dim3(256), 0, stream, hs, hsb);
    hipLaunchKernelGGL(transpose_f32_bf16, dim3(NQKVZ / 32, HID / 32), dim3(256), 0, stream,
                       Wqkvz, WqkvzT, HID, NQKVZ);
    hipLaunchKernelGGL(transpose_f32_bf16, dim3(2048 / 32, 2048 / 32), dim3(256), 0, stream,
                       Wout, WoutT, 2048, 2048);
    hipLaunchKernelGGL(transpose_f32_f32, dim3(1, HID / 32), dim3(256), 0, stream,
                       Wba, WbaT, HID, 32);

    // 2. GEMM1: qkvz = hs @ W_qkvz
    hipLaunchKernelGGL((gemm_abT<u16>), dim3(NQKVZ / BN, 4096 / BM), dim3(256), 0, stream,
                       hsb, WqkvzT, qkvz, 4096, NQKVZ, HID);

    // 3. ba -> g, beta
    hipLaunchKernelGGL(ba_kernel, dim3(4096), dim3(64), 0, stream,
                       hs, WbaT, A_log, dtb, gs, bs);

    // 4. conv + l2norm -> q,k,v (bf16)
    hipLaunchKernelGGL(conv_qkv, dim3(4096), dim3(256), 0, stream,
                       qkvz, convw, convb, qs, ks, vs);

    // 5a. chunk prep (parallel): T, P, wb, ql, kd, gam
    hipLaunchKernelGGL(gdn_prep, dim3(1024), dim3(256), 0, stream,
                       ks, qs, gs, bs, Tbuf, Pbuf, wbq, qlq, kdq, gamb);

    // 5b. chunk recurrence (MFMA, GLOAD-staged, S0-in-registers)
    hipLaunchKernelGGL(gdn_chunk, dim3(256), dim3(256), 0, stream,
                       vs, bs, Tbuf, Pbuf, wbq, qlq, kdq, gamb, os);

    // 6. gated RMS norm -> bf16 A2
    hipLaunchKernelGGL(gated_norm, dim3(4096 * NH), dim3(128), 0, stream,
                       os, qkvz, normw, A2);

    // 7. GEMM2: out = A2 @ W_out
    hipLaunchKernelGGL((gemm_abT<float>), dim3(2048 / BN, 4096 / BM), dim3(256), 0, stream,
                       A2, WoutT, (float*)d_out, 4096, 2048, HID);
}

// Round 10
// 689.284 us; speedup vs baseline: 1.3558x; 1.1475x over previous
//
#include <hip/hip_runtime.h>

typedef unsigned short u16;
typedef unsigned int u32;
typedef short short8 __attribute__((ext_vector_type(8)));
typedef float float4v __attribute__((ext_vector_type(4)));

#define L_SEQ 1024
#define NB 4
#define NH 16
#define DK 128
#define DV 128
#define HID 2048
#define NQKVZ 8192
#define CONV_DIM 6144
#define GDN_SCALE 0.08838834764831845f  // 128^-0.5

static __device__ __forceinline__ float bf2f(u16 u) {
    union { u32 i; float f; } x; x.i = ((u32)u) << 16; return x.f;
}
static __device__ __forceinline__ u16 f2bf(float f) {
    union { float f; u32 u; } x; x.f = f;
    u32 r = x.u + 0x7FFF + ((x.u >> 16) & 1);
    return (u16)(r >> 16);
}

union FragU { short8 v; uint4 u; };

// async global->LDS, 16B per lane (lane-contiguous LDS dest required).
#define GLOAD_LDS16(g, l)                                        \
    __builtin_amdgcn_global_load_lds(                            \
        (const __attribute__((address_space(1))) void*)(g),      \
        (__attribute__((address_space(3))) void*)(l), 16, 0, 0)

// ---------------- fp32 -> bf16 elementwise convert ---------------------------
__global__ __launch_bounds__(256) void f32_to_bf16(
    const float* __restrict__ in, u16* __restrict__ out) {
    long i = ((long)blockIdx.x * 256 + threadIdx.x) * 8;
    float4 a = *(const float4*)(in + i);
    float4 b = *(const float4*)(in + i + 4);
    u16 tmp[8];
    tmp[0] = f2bf(a.x); tmp[1] = f2bf(a.y); tmp[2] = f2bf(a.z); tmp[3] = f2bf(a.w);
    tmp[4] = f2bf(b.x); tmp[5] = f2bf(b.y); tmp[6] = f2bf(b.z); tmp[7] = f2bf(b.w);
    *(uint4*)(out + i) = *(const uint4*)tmp;
}

// ---------------- transpose fp32 (RxC) -> bf16 (CxR) -------------------------
__global__ __launch_bounds__(256) void transpose_f32_bf16(
    const float* __restrict__ in, u16* __restrict__ out, int R, int C) {
    __shared__ float tile[32][33];
    int bx = blockIdx.x, by = blockIdx.y;
    int c = threadIdx.x & 31;
    int r0 = threadIdx.x >> 5;
#pragma unroll
    for (int i = 0; i < 4; i++) {
        int r = r0 + i * 8;
        tile[r][c] = in[(long)(by * 32 + r) * C + bx * 32 + c];
    }
    __syncthreads();
#pragma unroll
    for (int i = 0; i < 4; i++) {
        int r = r0 + i * 8;
        out[(long)(bx * 32 + r) * R + by * 32 + c] = f2bf(tile[c][r]);
    }
}

// ---------------- GEMM (m97 structure): C = A * BT^T, bf16 in, OutT out ------
#define BM 128
#define BN 128
#define BKK 32

static __device__ __forceinline__ void store_out(u16* p, float v)  { *p = f2bf(v); }
static __device__ __forceinline__ void store_out(float* p, float v){ *p = v; }

template <typename OutT>
__global__ __launch_bounds__(256) void gemm_abT(
    const u16* __restrict__ A, const u16* __restrict__ BT,
    OutT* __restrict__ C, int M, int N, int K) {
    __shared__ u16 As[BM * BKK];
    __shared__ u16 Bs[BN * BKK];
    int t = threadIdx.x;
    int lane = t & 63;
    int w = t >> 6;
    int wm = (w & 1) * 64;
    int wn = (w >> 1) * 64;
    int l15 = lane & 15;
    int quad = lane >> 4;
    long blockM = (long)blockIdx.y * BM;
    long blockN = (long)blockIdx.x * BN;

    float4v acc[4][4];
#pragma unroll
    for (int i = 0; i < 4; i++)
#pragma unroll
        for (int j = 0; j < 4; j++) acc[i][j] = (float4v){0.f, 0.f, 0.f, 0.f};

    const u16* Ab = A + blockM * K;
    const u16* Bb = BT + blockN * K;

    const int r0 = t >> 2,         c0 = (t & 3) * 8;
    const int r1 = (t + 256) >> 2, c1 = ((t + 256) & 3) * 8;
    u16* As0 = As + t * 8;         u16* As1 = As + (t + 256) * 8;
    u16* Bs0 = Bs + t * 8;         u16* Bs1 = Bs + (t + 256) * 8;
    const u16* Ag0 = Ab + (long)r0 * K + c0;
    const u16* Ag1 = Ab + (long)r1 * K + c1;
    const u16* Bg0 = Bb + (long)r0 * K + c0;
    const u16* Bg1 = Bb + (long)r1 * K + c1;

    for (int k0 = 0; k0 < K; k0 += BKK) {
        __syncthreads();
        GLOAD_LDS16(Ag0 + k0, As0);
        GLOAD_LDS16(Ag1 + k0, As1);
        GLOAD_LDS16(Bg0 + k0, Bs0);
        GLOAD_LDS16(Bg1 + k0, Bs1);
        __syncthreads();

        FragU fa[4], fb[4];
#pragma unroll
        for (int i = 0; i < 4; i++) {
            fa[i].u = *(const uint4*)(As + (wm + i * 16 + l15) * BKK + quad * 8);
            fb[i].u = *(const uint4*)(Bs + (wn + i * 16 + l15) * BKK + quad * 8);
        }
#pragma unroll
        for (int i = 0; i < 4; i++)
#pragma unroll
            for (int j = 0; j < 4; j++)
                acc[i][j] = __builtin_amdgcn_mfma_f32_16x16x32_bf16(
                    fa[i].v, fb[j].v, acc[i][j], 0, 0, 0);
    }

#pragma unroll
    for (int i = 0; i < 4; i++) {
        long mrow = blockM + wm + i * 16 + quad * 4;
#pragma unroll
        for (int j = 0; j < 4; j++) {
            long col = blockN + wn + j * 16 + l15;
#pragma unroll
            for (int r = 0; r < 4; r++) {
                store_out(&C[(mrow + r) * N + col], acc[i][j][r]);
            }
        }
    }
}

// ---------------- ba as MFMA GEMM + fused epilogue ---------------------------
// 32 blocks x 256 thr. M=128/block, N=32, K=2048. A=hsb, BT=WbaTb (32x2048).
// NOTE: A tile is 128x32 = 8 KB = TWO 4 KB global_load_lds passes (r9 bug fix).
__global__ __launch_bounds__(256) void ba_gemm(
    const u16* __restrict__ hsb, const u16* __restrict__ WbaTb,
    const float* __restrict__ A_log, const float* __restrict__ dtb,
    float* __restrict__ gout, float* __restrict__ bout) {
    __shared__ u16 As[128 * 32];
    __shared__ u16 Bs[32 * 32];
    int t = threadIdx.x;
    int lane = t & 63, w = t >> 6, l15 = lane & 15, quad = lane >> 4;
    int wm = w * 32;
    long blockM = (long)blockIdx.x * 128;

    float4v acc[2][2];
#pragma unroll
    for (int i = 0; i < 2; i++)
#pragma unroll
        for (int j = 0; j < 2; j++) acc[i][j] = (float4v){0.f, 0.f, 0.f, 0.f};

    const u16* Ab = hsb + blockM * HID;
    const int r0 = t >> 2,         c0 = (t & 3) * 8;
    const int r1 = (t + 256) >> 2, c1 = ((t + 256) & 3) * 8;
    u16* As0 = As + t * 8;
    u16* As1 = As + (t + 256) * 8;
    const u16* Ag0 = Ab + (long)r0 * HID + c0;
    const u16* Ag1 = Ab + (long)r1 * HID + c1;
    const u16* Bg  = WbaTb + (long)(t >> 2) * HID + (t & 3) * 8;  // valid t<128

    for (int k0 = 0; k0 < HID; k0 += 32) {
        __syncthreads();
        GLOAD_LDS16(Ag0 + k0, As0);
        GLOAD_LDS16(Ag1 + k0, As1);
        if (t < 128) GLOAD_LDS16(Bg + k0, Bs + t * 8);
        __syncthreads();
        FragU fa[2], fb[2];
#pragma unroll
        for (int i = 0; i < 2; i++) {
            fa[i].u = *(const uint4*)(As + (wm + i * 16 + l15) * 32 + quad * 8);
            fb[i].u = *(const uint4*)(Bs + (i * 16 + l15) * 32 + quad * 8);
        }
#pragma unroll
        for (int i = 0; i < 2; i++)
#pragma unroll
            for (int j = 0; j < 2; j++)
                acc[i][j] = __builtin_amdgcn_mfma_f32_16x16x32_bf16(
                    fa[i].v, fb[j].v, acc[i][j], 0, 0, 0);
    }

#pragma unroll
    for (int i = 0; i < 2; i++) {
#pragma unroll
        for (int j = 0; j < 2; j++) {
            int n = j * 16 + l15;
#pragma unroll
            for (int r = 0; r < 4; r++) {
                long m = blockM + wm + i * 16 + quad * 4 + r;
                int b = (int)(m >> 10), l = (int)(m & 1023);
                float v = acc[i][j][r];
                if (n < 16) {
                    bout[((long)(b * NH + n)) * L_SEQ + l] = 1.f / (1.f + expf(-v));
                } else {
                    int h = n - 16;
                    float x = v + dtb[h];
                    float sp = (x > 20.f) ? x : log1pf(expf(x));
                    gout[((long)(b * NH + h)) * L_SEQ + l] = -expf(A_log[h]) * sp;
                }
            }
        }
    }
}

// ---------------- conv(KS=4) + l2norm(q,k) + split v -> bf16 -----------------
__global__ __launch_bounds__(256) void conv_qkv(
    const u16* __restrict__ qkvz, const float* __restrict__ conv_w,
    const float* __restrict__ conv_b,
    u16* __restrict__ qs, u16* __restrict__ ks, u16* __restrict__ vs) {
    int bl = blockIdx.x;  // b*L + l
    int b = bl >> 10, l = bl & 1023;
    int t = threadIdx.x;
    __shared__ float xb[CONV_DIM];
    __shared__ float red[32][9];
    __shared__ float rbuf[32];

    for (int c = t; c < CONV_DIM; c += 256) {
        float acc = conv_b[c];
        float w0 = conv_w[c * 4 + 0];
        float w1 = conv_w[c * 4 + 1];
        float w2 = conv_w[c * 4 + 2];
        float w3 = conv_w[c * 4 + 3];
        long rowbase = (long)(b * L_SEQ) * NQKVZ + c;
        if (l - 3 >= 0) acc += bf2f(qkvz[rowbase + (long)(l - 3) * NQKVZ]) * w0;
        if (l - 2 >= 0) acc += bf2f(qkvz[rowbase + (long)(l - 2) * NQKVZ]) * w1;
        if (l - 1 >= 0) acc += bf2f(qkvz[rowbase + (long)(l - 1) * NQKVZ]) * w2;
        acc += bf2f(qkvz[rowbase + (long)l * NQKVZ]) * w3;
        xb[c] = acc;
    }
    __syncthreads();
    {
        int grp = t >> 3;
        int j8 = t & 7;
        float s = 0.f;
#pragma unroll
        for (int i = 0; i < 16; i++) {
            float xv = xb[grp * 128 + j8 * 16 + i];
            s += xv * xv;
        }
        red[grp][j8] = s;
    }
    __syncthreads();
    if (t < 32) {
        float s = 0.f;
#pragma unroll
        for (int i = 0; i < 8; i++) s += red[t][i];
        rbuf[t] = rsqrtf(s + 1e-6f);
    }
    __syncthreads();
    for (int c = t; c < CONV_DIM; c += 256) {
        float xv = xb[c];
        if (c < 2048) {
            int h = c >> 7, d = c & 127;
            qs[(((long)(b * NH + h)) * L_SEQ + l) * DK + d] = f2bf(xv * rbuf[h]);
        } else if (c < 4096) {
            int c2 = c - 2048;
            int h = c2 >> 7, d = c2 & 127;
            ks[(((long)(b * NH + h)) * L_SEQ + l) * DK + d] = f2bf(xv * rbuf[16 + h]);
        } else {
            int c2 = c - 4096;
            int h = c2 >> 7, d = c2 & 127;
            vs[(((long)(b * NH + h)) * L_SEQ + l) * DV + d] = f2bf(xv);
        }
    }
}

// ---------------- gdn_prep v2: per-chunk T, P, wb, ql, kd, gam ---------------
// 1024 blocks = (bh=64) x (chunk=16); 256 threads (4 waves).
// Prefix scan via shuffle; fwd-subst = 2 parallel 32x32 (waves 0,1) +
// all-thread VALU combine T21 = -T22*A21*T11.
__global__ __launch_bounds__(256) void gdn_prep(
    const u16* __restrict__ ks_g, const u16* __restrict__ qs_g,
    const float* __restrict__ g_g, const float* __restrict__ b_g,
    u16* __restrict__ Tbuf, u16* __restrict__ Pbuf,
    u16* __restrict__ wbq, u16* __restrict__ qlq, u16* __restrict__ kdq,
    float* __restrict__ gam_g) {
    int cid = blockIdx.x;
    int bh = cid >> 4;
    int ch = cid & 15;
    long rowbase = (long)bh * L_SEQ + ch * 64;
    int t = threadIdx.x;
    int lane = t & 63, w = t >> 6, l15 = lane & 15, quad = lane >> 4;

    __shared__ u16 Kl[64 * 136];
    __shared__ u16 Ql[64 * 136];
    __shared__ float Am[64 * 66];
    __shared__ float Tm[64 * 66];
    __shared__ float Tt[32 * 33];
    __shared__ float Gs[64], lamL[64], betaL[64], dlL[64];

    {   // stage K,Q rows bf16 -> padded LDS; stage g, beta
        int row = t >> 2, seg = (t & 3) * 32;
        const u16* ksrc = ks_g + (rowbase + row) * DK + seg;
        const u16* qsrc = qs_g + (rowbase + row) * DK + seg;
        *(uint4*)&Kl[row * 136 + seg]      = *(const uint4*)ksrc;
        *(uint4*)&Kl[row * 136 + seg + 8]  = *(const uint4*)(ksrc + 8);
        *(uint4*)&Kl[row * 136 + seg + 16] = *(const uint4*)(ksrc + 16);
        *(uint4*)&Kl[row * 136 + seg + 24] = *(const uint4*)(ksrc + 24);
        *(uint4*)&Ql[row * 136 + seg]      = *(const uint4*)qsrc;
        *(uint4*)&Ql[row * 136 + seg + 8]  = *(const uint4*)(qsrc + 8);
        *(uint4*)&Ql[row * 136 + seg + 16] = *(const uint4*)(qsrc + 16);
        *(uint4*)&Ql[row * 136 + seg + 24] = *(const uint4*)(qsrc + 24);
        if (t < 64) Gs[t] = g_g[rowbase + t];
        else if (t < 128) betaL[t - 64] = b_g[rowbase + t - 64];
    }
    __syncthreads();
    if (t < 64) {   // inclusive prefix scan (Kogge-Stone, wave 0)
        float gv = Gs[t];
#pragma unroll
        for (int off = 1; off < 64; off <<= 1) {
            float n = __shfl_up(gv, off);
            if (lane >= off) gv += n;
        }
        Gs[t] = gv;
    }
    __syncthreads();
    if (t < 64) {
        float G63 = Gs[63];
        float lm = expf(Gs[t]);
        lamL[t] = lm;
        dlL[t] = expf(G63 - Gs[t]);
        if (t == 0) gam_g[cid] = expf(G63);
    }
    // MFMA: KK^T and QK^T (wave w = row-stripe w*16)
    float4v accKK[4], accQK[4];
#pragma unroll
    for (int tj = 0; tj < 4; tj++) {
        accKK[tj] = (float4v){0.f, 0.f, 0.f, 0.f};
        accQK[tj] = (float4v){0.f, 0.f, 0.f, 0.f};
    }
#pragma unroll
    for (int k0 = 0; k0 < 128; k0 += 32) {
        FragU ka, qa;
        ka.u = *(const uint4*)&Kl[(w * 16 + l15) * 136 + k0 + quad * 8];
        qa.u = *(const uint4*)&Ql[(w * 16 + l15) * 136 + k0 + quad * 8];
#pragma unroll
        for (int tj = 0; tj < 4; tj++) {
            FragU kb;
            kb.u = *(const uint4*)&Kl[(tj * 16 + l15) * 136 + k0 + quad * 8];
            accKK[tj] = __builtin_amdgcn_mfma_f32_16x16x32_bf16(ka.v, kb.v, accKK[tj], 0, 0, 0);
            accQK[tj] = __builtin_amdgcn_mfma_f32_16x16x32_bf16(qa.v, kb.v, accQK[tj], 0, 0, 0);
        }
    }
    __syncthreads();   // lamL/betaL/dlL visible
    // mask + scale; Am -> LDS fp32, P -> global bf16
#pragma unroll
    for (int tj = 0; tj < 4; tj++) {
#pragma unroll
        for (int r = 0; r < 4; r++) {
            int ti_ = w * 16 + quad * 4 + r;
            int j = tj * 16 + l15;
            float e = (j <= ti_) ? expf(Gs[ti_] - Gs[j]) : 0.f;
            Am[ti_ * 66 + j] = (j < ti_) ? betaL[ti_] * e * accKK[tj][r] : 0.f;
            Pbuf[(long)cid * 4096 + ti_ * 64 + j] =
                (j <= ti_) ? f2bf(GDN_SCALE * e * accQK[tj][r]) : (u16)0;
        }
    }
    // wbq, qlq (row-major [64][128])
    {
        int row = t >> 2, seg = (t & 3) * 32;
        float sw = -betaL[row] * lamL[row];
        float sq = GDN_SCALE * lamL[row];
#pragma unroll
        for (int c0 = 0; c0 < 32; c0 += 8) {
            u16 wt[8], qt2[8];
#pragma unroll
            for (int j2 = 0; j2 < 8; j2++) {
                wt[j2]  = f2bf(sw * bf2f(Kl[row * 136 + seg + c0 + j2]));
                qt2[j2] = f2bf(sq * bf2f(Ql[row * 136 + seg + c0 + j2]));
            }
            *(uint4*)&wbq[(long)cid * 8192 + row * 128 + seg + c0] = *(uint4*)wt;
            *(uint4*)&qlq[(long)cid * 8192 + row * 128 + seg + c0] = *(uint4*)qt2;
        }
    }
    // kdq (transposed [128 k][64 t]) — all 256 threads
    {
        int k = t & 127, t0b = (t >> 7) * 32;
#pragma unroll
        for (int t0 = 0; t0 < 32; t0 += 8) {
            u16 tmp[8];
#pragma unroll
            for (int j2 = 0; j2 < 8; j2++)
                tmp[j2] = f2bf(dlL[t0b + t0 + j2] * bf2f(Kl[(t0b + t0 + j2) * 136 + k]));
            *(uint4*)&kdq[(long)cid * 8192 + k * 64 + t0b + t0] = *(uint4*)tmp;
        }
    }
    __syncthreads();
    // fwd-subst: T11 (lanes 0-31 of wave 0), T22 (lanes 0-31 of wave 1), zero T12
    if (t < 32) {
        int c = t;
        for (int i = 0; i < 32; i++) {
            float s = (i == c) ? 1.f : 0.f;
            for (int j = 0; j < i; j++) s -= Am[i * 66 + j] * Tm[j * 66 + c];
            Tm[i * 66 + c] = s;
        }
    } else if (t >= 64 && t < 96) {
        int c = 32 + (t - 64);
        for (int i = 32; i < 64; i++) {
            float s = (i == c) ? 1.f : 0.f;
            for (int j = 32; j < i; j++) s -= Am[i * 66 + j] * Tm[j * 66 + c];
            Tm[i * 66 + c] = s;
        }
    } else if (t >= 128 && t < 192) {
        int idx = t - 128;
        for (int kk = 0; kk < 16; kk++) {
            int e = idx * 16 + kk;
            Tm[(e >> 5) * 66 + 32 + (e & 31)] = 0.f;
        }
    }
    __syncthreads();
    {   // Tt = A21 * T11  (32x32, 4 elems/thread)
        int e0 = t * 4;
#pragma unroll
        for (int kk = 0; kk < 4; kk++) {
            int e = e0 + kk; int i = e >> 5, c = e & 31;
            float s = 0.f;
            for (int j = 0; j < 32; j++) s += Am[(32 + i) * 66 + j] * Tm[j * 66 + c];
            Tt[i * 33 + c] = s;
        }
    }
    __syncthreads();
    {   // T21 = -T22 * Tt
        int e0 = t * 4;
#pragma unroll
        for (int kk = 0; kk < 4; kk++) {
            int e = e0 + kk; int i = e >> 5, c = e & 31;
            float s = 0.f;
            for (int j = 0; j < 32; j++) s -= Tm[(32 + i) * 66 + 32 + j] * Tt[j * 33 + c];
            Tm[(32 + i) * 66 + c] = s;
        }
    }
    __syncthreads();
    {   // T -> global bf16
        int row = t >> 2, c0 = (t & 3) * 16;
        u16 tmp[16];
#pragma unroll
        for (int i = 0; i < 16; i++) tmp[i] = f2bf(Tm[row * 66 + c0 + i]);
        *(uint4*)&Tbuf[(long)cid * 4096 + row * 64 + c0]     = *(uint4*)tmp;
        *(uint4*)&Tbuf[(long)cid * 4096 + row * 64 + c0 + 8] = *(uint4*)(tmp + 8);
    }
}

// ---------------- gdn_chunk v3: direct-global fragments, 512 blocks ----------
// 512 blocks = (bh=64) x (dc=8: 16 v-cols). 256 threads (4 waves).
// T/P/wb/ql/kd fragments loaded global->VGPR (each read once per block);
// only block-produced tiles (S0 split, vb/O, rhsT, DT) live in LDS (~19 KB).
// S0^T in registers: wave w owns k-tiles {2w,2w+1} (all 16 v rows).
__global__ __launch_bounds__(256) void gdn_chunk(
    const u16* __restrict__ vs_g, const float* __restrict__ b_g,
    const u16* __restrict__ Tq, const u16* __restrict__ Pq,
    const u16* __restrict__ wbq, const u16* __restrict__ qlq,
    const u16* __restrict__ kdq, const float* __restrict__ gam_g,
    float* __restrict__ o_g) {
    int bid = blockIdx.x;
    int dc = bid & 7;
    int bh = bid >> 3;
    int b = bh >> 4, h = bh & 15;
    int t = threadIdx.x;
    int lane = t & 63, w = t >> 6, l15 = lane & 15, quad = lane >> 4;

    __shared__ u16 s0h[16 * 136], s0l[16 * 136];   // S0^T [v][k] hi/lo
    __shared__ float vO[64 * 20];                  // vb / O, [t][v]
    __shared__ u16 rhsT[16 * 72], DT[16 * 72];     // [v][t]

    float4v S0r[2];
    S0r[0] = (float4v){0.f, 0.f, 0.f, 0.f};
    S0r[1] = (float4v){0.f, 0.f, 0.f, 0.f};

    const int orow = t >> 2, oseg = (t & 3) * 4;   // 64 rows x 16 cols

    for (int ch = 0; ch < 16; ch++) {
        int cid = bh * 16 + ch;
        long rowbase = (long)bh * L_SEQ + ch * 64;
        float gam = gam_g[cid];

        // prefetch wb fragments (used phase b)
        const u16* wbp = wbq + (long)cid * 8192 + (w * 16 + l15) * 128 + quad * 8;
        uint4 wbf0 = *(const uint4*)(wbp);
        uint4 wbf1 = *(const uint4*)(wbp + 32);
        uint4 wbf2 = *(const uint4*)(wbp + 64);
        uint4 wbf3 = *(const uint4*)(wbp + 96);

        // ---- phase a: store prev O, load vb, split S0 ----
        if (ch > 0) {
            float4 a = *(const float4*)&vO[orow * 20 + oseg];
            float* d2 = o_g + (((long)b * L_SEQ + (ch - 1) * 64 + orow) * 16 + h) * 128L
                        + dc * 16 + oseg;
            *(float4*)d2 = a;
        }
        {
            float beta = b_g[rowbase + orow];
            uint2 vv = *(const uint2*)(vs_g + (rowbase + orow) * DV + dc * 16 + oseg);
            const u16* vp = (const u16*)&vv;
#pragma unroll
            for (int j2 = 0; j2 < 4; j2++)
                vO[orow * 20 + oseg + j2] = beta * bf2f(vp[j2]);
        }
#pragma unroll
        for (int ktl = 0; ktl < 2; ktl++) {
            int kc = (2 * w + ktl) * 16 + l15;
#pragma unroll
            for (int r = 0; r < 4; r++) {
                float x = S0r[ktl][r];
                u16 hi = f2bf(x);
                float lo = x - bf2f(hi);
                s0h[(quad * 4 + r) * 136 + kc] = hi;
                s0l[(quad * 4 + r) * 136 + kc] = f2bf(lo);
            }
        }
        __syncthreads();

        // ---- phase b: RHS[t][v] = vb + wb*(S0h+S0l) -> rhsT ----
        const u16* Tp = Tq + (long)cid * 4096 + (w * 16 + l15) * 64 + quad * 8;
        uint4 Tf0 = *(const uint4*)(Tp);        // prefetch for phase c
        uint4 Tf1 = *(const uint4*)(Tp + 32);
        {
            float4v acc;
#pragma unroll
            for (int r = 0; r < 4; r++)
                acc[r] = vO[(w * 16 + quad * 4 + r) * 20 + l15];
            uint4 wbf[4] = {wbf0, wbf1, wbf2, wbf3};
#pragma unroll
            for (int k0 = 0; k0 < 4; k0++) {
                FragU a, bh_, bl_;
                a.u = wbf[k0];
                bh_.u = *(const uint4*)&s0h[l15 * 136 + k0 * 32 + quad * 8];
                acc = __builtin_amdgcn_mfma_f32_16x16x32_bf16(a.v, bh_.v, acc, 0, 0, 0);
                bl_.u = *(const uint4*)&s0l[l15 * 136 + k0 * 32 + quad * 8];
                acc = __builtin_amdgcn_mfma_f32_16x16x32_bf16(a.v, bl_.v, acc, 0, 0, 0);
            }
            u16 tmp[4] = {f2bf(acc[0]), f2bf(acc[1]), f2bf(acc[2]), f2bf(acc[3])};
            *(uint2*)&rhsT[l15 * 72 + w * 16 + quad * 4] = *(uint2*)tmp;
        }
        __syncthreads();

        // ---- phase c: D = T*RHS -> DT ----
        const u16* qlp = qlq + (long)cid * 8192 + (w * 16 + l15) * 128 + quad * 8;
        uint4 qlf0 = *(const uint4*)(qlp);      // prefetch for phase d
        uint4 qlf1 = *(const uint4*)(qlp + 32);
        uint4 qlf2 = *(const uint4*)(qlp + 64);
        uint4 qlf3 = *(const uint4*)(qlp + 96);
        const u16* Pp = Pq + (long)cid * 4096 + (w * 16 + l15) * 64 + quad * 8;
        uint4 Pf0 = *(const uint4*)(Pp);
        uint4 Pf1 = *(const uint4*)(Pp + 32);
        {
            float4v acc = (float4v){0.f, 0.f, 0.f, 0.f};
            uint4 Tf[2] = {Tf0, Tf1};
#pragma unroll
            for (int k0 = 0; k0 < 2; k0++) {
                FragU a, b_;
                a.u = Tf[k0];
                b_.u = *(const uint4*)&rhsT[l15 * 72 + k0 * 32 + quad * 8];
                acc = __builtin_amdgcn_mfma_f32_16x16x32_bf16(a.v, b_.v, acc, 0, 0, 0);
            }
            u16 tmp[4] = {f2bf(acc[0]), f2bf(acc[1]), f2bf(acc[2]), f2bf(acc[3])};
            *(uint2*)&DT[l15 * 72 + w * 16 + quad * 4] = *(uint2*)tmp;
        }
        __syncthreads();

        // ---- phase d: O = ql*S0 + P*D ; S0 = gam*S0 + kd^T D ----
        uint4 kdf[2][2];
#pragma unroll
        for (int ktl = 0; ktl < 2; ktl++) {
            const u16* kdp = kdq + (long)cid * 8192 + ((2 * w + ktl) * 16 + l15) * 64 + quad * 8;
            kdf[ktl][0] = *(const uint4*)(kdp);
            kdf[ktl][1] = *(const uint4*)(kdp + 32);
        }
        {
            float4v acc = (float4v){0.f, 0.f, 0.f, 0.f};
            uint4 qlf[4] = {qlf0, qlf1, qlf2, qlf3};
#pragma unroll
            for (int k0 = 0; k0 < 4; k0++) {
                FragU a, bh_, bl_;
                a.u = qlf[k0];
                bh_.u = *(const uint4*)&s0h[l15 * 136 + k0 * 32 + quad * 8];
                acc = __builtin_amdgcn_mfma_f32_16x16x32_bf16(a.v, bh_.v, acc, 0, 0, 0);
                bl_.u = *(const uint4*)&s0l[l15 * 136 + k0 * 32 + quad * 8];
                acc = __builtin_amdgcn_mfma_f32_16x16x32_bf16(a.v, bl_.v, acc, 0, 0, 0);
            }
            uint4 Pf[2] = {Pf0, Pf1};
#pragma unroll
            for (int k0 = 0; k0 < 2; k0++) {
                FragU a, b_;
                a.u = Pf[k0];
                b_.u = *(const uint4*)&DT[l15 * 72 + k0 * 32 + quad * 8];
                acc = __builtin_amdgcn_mfma_f32_16x16x32_bf16(a.v, b_.v, acc, 0, 0, 0);
            }
#pragma unroll
            for (int r = 0; r < 4; r++)
                vO[(w * 16 + quad * 4 + r) * 20 + l15] = acc[r];
        }
#pragma unroll
        for (int ktl = 0; ktl < 2; ktl++) {
            float4v acc = S0r[ktl];
#pragma unroll
            for (int r = 0; r < 4; r++) acc[r] *= gam;
#pragma unroll
            for (int t0 = 0; t0 < 2; t0++) {
                FragU a, b_;
                a.u = *(const uint4*)&DT[l15 * 72 + t0 * 32 + quad * 8];
                b_.u = kdf[ktl][t0];
                acc = __builtin_amdgcn_mfma_f32_16x16x32_bf16(a.v, b_.v, acc, 0, 0, 0);
            }
            S0r[ktl] = acc;
        }
        __syncthreads();
    }
    // final chunk's O store
    {
        float4 a = *(const float4*)&vO[orow * 20 + oseg];
        float* d2 = o_g + (((long)b * L_SEQ + 15 * 64 + orow) * 16 + h) * 128L
                    + dc * 16 + oseg;
        *(float4*)d2 = a;
    }
}

// ---------------- gated RMS norm -> bf16 A2 ----------------------------------
__global__ __launch_bounds__(128) void gated_norm(
    const float* __restrict__ o, const u16* __restrict__ qkvz,
    const float* __restrict__ norm_w, u16* __restrict__ A2) {
    int bid = blockIdx.x;  // (b*L+l)*16 + h
    int t = threadIdx.x;   // 0..127
    float ov = o[(long)bid * 128 + t];
    float s = ov * ov;
#pragma unroll
    for (int off = 32; off > 0; off >>= 1) s += __shfl_down(s, off);
    __shared__ float ws2[2];
    if ((t & 63) == 0) ws2[t >> 6] = s;
    __syncthreads();
    float tot = ws2[0] + ws2[1];
    float rinv = rsqrtf(tot * (1.f / 128.f) + 1e-6f);
    int bl = bid >> 4, h = bid & 15;
    float z = bf2f(qkvz[(long)bl * NQKVZ + CONV_DIM + h * 128 + t]);
    float sig = 1.f / (1.f + expf(-z));
    float val = ov * rinv * norm_w[t] * sig;
    A2[(long)bl * 2048 + h * 128 + t] = f2bf(val);
}

// ---------------- host-side launcher -----------------------------------------
extern "C" void kernel_launch(void* const* d_in, const int* in_sizes, int n_in,
                              void* d_out, int out_size, void* d_ws, size_t ws_size,
                              hipStream_t stream) {
    const float* hs    = (const float*)d_in[0];
    const float* Wqkvz = (const float*)d_in[1];
    const float* Wba   = (const float*)d_in[2];
    const float* convw = (const float*)d_in[3];
    const float* convb = (const float*)d_in[4];
    const float* A_log = (const float*)d_in[5];
    const float* dtb   = (const float*)d_in[6];
    const float* normw = (const float*)d_in[7];
    const float* Wout  = (const float*)d_in[8];

    char* ws = (char*)d_ws;
    size_t off = 0;
    auto alloc = [&](size_t bytes) {
        size_t o = off;
        off = (off + bytes + 255) & ~(size_t)255;
        return o;
    };
    // region0: WqkvzT (bf16) — dead after GEMM1, reused for os (fp32)
    size_t r0 = alloc((size_t)NQKVZ * HID * 2);
    // region1: hs_bf16 — kept through ba_gemm; A2 aliases after
    size_t r1 = alloc((size_t)4096 * HID * 2);
    u16*   WqkvzT = (u16*)(ws + r0);
    float* os     = (float*)(ws + r0);
    u16*   hsb    = (u16*)(ws + r1);
    u16*   A2     = (u16*)(ws + r1);   // written by gated_norm after ba_gemm done
    u16*   qkvz   = (u16*)(ws + alloc((size_t)4096 * NQKVZ * 2));
    u16*   qs     = (u16*)(ws + alloc((size_t)64 * L_SEQ * DK * 2));
    u16*   ks     = (u16*)(ws + alloc((size_t)64 * L_SEQ * DK * 2));
    u16*   vs     = (u16*)(ws + alloc((size_t)64 * L_SEQ * DV * 2));
    float* gs     = (float*)(ws + alloc((size_t)64 * L_SEQ * 4));
    float* bs     = (float*)(ws + alloc((size_t)64 * L_SEQ * 4));
    u16*   WoutT  = (u16*)(ws + alloc((size_t)HID * 2048 * 2));
    u16*   WbaTb  = (u16*)(ws + alloc((size_t)32 * HID * 2));
    u16*   Tbuf   = (u16*)(ws + alloc((size_t)1024 * 4096 * 2));
    u16*   Pbuf   = (u16*)(ws + alloc((size_t)1024 * 4096 * 2));
    u16*   wbq    = (u16*)(ws + alloc((size_t)1024 * 8192 * 2));
    u16*   qlq    = (u16*)(ws + alloc((size_t)1024 * 8192 * 2));
    u16*   kdq    = (u16*)(ws + alloc((size_t)1024 * 8192 * 2));
    float* gamb   = (float*)(ws + alloc((size_t)1024 * 4));

    // 1. convert + transposes
    hipLaunchKernelGGL(f32_to_bf16, dim3(4096), dim3(256), 0, stream, hs, hsb);
    hipLaunchKernelGGL(transpose_f32_bf16, dim3(NQKVZ / 32, HID / 32), dim3(256), 0, stream,
                       Wqkvz, WqkvzT, HID, NQKVZ);
    hipLaunchKernelGGL(transpose_f32_bf16, dim3(2048 / 32, 2048 / 32), dim3(256), 0, stream,
                       Wout, WoutT, 2048, 2048);
    hipLaunchKernelGGL(transpose_f32_bf16, dim3(1, HID / 32), dim3(256), 0, stream,
                       Wba, WbaTb, HID, 32);

    // 2. GEMM1: qkvz = hs @ W_qkvz
    hipLaunchKernelGGL((gemm_abT<u16>), dim3(NQKVZ / BN, 4096 / BM), dim3(256), 0, stream,
                       hsb, WqkvzT, qkvz, 4096, NQKVZ, HID);

    // 3. ba (MFMA) -> g, beta
    hipLaunchKernelGGL(ba_gemm, dim3(32), dim3(256), 0, stream,
                       hsb, WbaTb, A_log, dtb, gs, bs);

    // 4. conv + l2norm -> q,k,v (bf16)
    hipLaunchKernelGGL(conv_qkv, dim3(4096), dim3(256), 0, stream,
                       qkvz, convw, convb, qs, ks, vs);

    // 5a. chunk prep (parallel): T, P, wb, ql, kd, gam
    hipLaunchKernelGGL(gdn_prep, dim3(1024), dim3(256), 0, stream,
                       ks, qs, gs, bs, Tbuf, Pbuf, wbq, qlq, kdq, gamb);

    // 5b. chunk recurrence (MFMA, direct-global fragments, 512 blocks)
    hipLaunchKernelGGL(gdn_chunk, dim3(512), dim3(256), 0, stream,
                       vs, bs, Tbuf, Pbuf, wbq, qlq, kdq, gamb, os);

    // 6. gated RMS norm -> bf16 A2
    hipLaunchKernelGGL(gated_norm, dim3(4096 * NH), dim3(128), 0, stream,
                       os, qkvz, normw, A2);

    // 7. GEMM2: out = A2 @ W_out
    hipLaunchKernelGGL((gemm_abT<float>), dim3(2048 / BN, 4096 / BM), dim3(256), 0, stream,
                       A2, WoutT, (float*)d_out, 4096, 2048, HID);
}